// Round 1
// baseline (3468.494 us; speedup 1.0000x reference)
//
#include <hip/hip_runtime.h>
#include <math.h>

#define T_SEQ  2048
#define C_DIM  2048
#define H_NUM  16
#define D_HEAD 128
#define MEM_N  1024
#define QKV_N  6144   // 3*C

// ================= GEMM: C[M,N] = A[M,K] @ B[K,N] + bias[N] =================
// 128x128 tile, BK=16, 256 threads, 8x8 micro-tile (split as 2x 4-row / 4-col
// chunks at +0 and +64 so LDS micro-reads are float4 with <=2-way conflicts).
__global__ __launch_bounds__(256, 2)
void gemm_bias_kernel(const float* __restrict__ A, const float* __restrict__ B,
                      const float* __restrict__ bias, float* __restrict__ C,
                      int M, int N, int K)
{
    __shared__ float As[16][132];   // A^T tile: As[k][m]
    __shared__ float Bs[16][132];   // Bs[k][n]

    const int tid = threadIdx.x;
    const int tx = tid & 15, ty = tid >> 4;
    const int bm = blockIdx.y * 128, bn = blockIdx.x * 128;

    const int lar = tid >> 2;            // A row in tile (and +64)
    const int lak = (tid & 3) << 2;      // A k offset (float4)
    const int lbk = tid >> 4;            // B k row
    const int lbn = (tid & 15) << 3;     // B col offset (2x float4)

    const float* pA0 = A + (size_t)(bm + lar) * K + lak;
    const float* pA1 = A + (size_t)(bm + 64 + lar) * K + lak;
    const float* pB  = B + (size_t)lbk * N + bn + lbn;

    float acc[8][8];
#pragma unroll
    for (int i = 0; i < 8; ++i)
#pragma unroll
        for (int j = 0; j < 8; ++j) acc[i][j] = 0.f;

    for (int kt = 0; kt < K; kt += 16) {
        const float4 a0 = *(const float4*)(pA0 + kt);
        const float4 a1 = *(const float4*)(pA1 + kt);
        const float4 b0 = *(const float4*)(pB + (size_t)kt * N);
        const float4 b1 = *(const float4*)(pB + (size_t)kt * N + 4);
        __syncthreads();   // previous compute done reading LDS
        As[lak + 0][lar] = a0.x; As[lak + 1][lar] = a0.y;
        As[lak + 2][lar] = a0.z; As[lak + 3][lar] = a0.w;
        As[lak + 0][64 + lar] = a1.x; As[lak + 1][64 + lar] = a1.y;
        As[lak + 2][64 + lar] = a1.z; As[lak + 3][64 + lar] = a1.w;
        *(float4*)&Bs[lbk][lbn]     = b0;
        *(float4*)&Bs[lbk][lbn + 4] = b1;
        __syncthreads();
#pragma unroll
        for (int kk = 0; kk < 16; ++kk) {
            const float4 av0 = *(const float4*)&As[kk][ty << 2];
            const float4 av1 = *(const float4*)&As[kk][64 + (ty << 2)];
            const float4 bv0 = *(const float4*)&Bs[kk][tx << 2];
            const float4 bv1 = *(const float4*)&Bs[kk][64 + (tx << 2)];
            const float a[8]  = {av0.x, av0.y, av0.z, av0.w, av1.x, av1.y, av1.z, av1.w};
            const float bb[8] = {bv0.x, bv0.y, bv0.z, bv0.w, bv1.x, bv1.y, bv1.z, bv1.w};
#pragma unroll
            for (int i = 0; i < 8; ++i)
#pragma unroll
                for (int j = 0; j < 8; ++j)
                    acc[i][j] = fmaf(a[i], bb[j], acc[i][j]);
        }
    }

    const float4 bs0 = *(const float4*)&bias[bn + (tx << 2)];
    const float4 bs1 = *(const float4*)&bias[bn + 64 + (tx << 2)];
    const float bb0[4] = {bs0.x, bs0.y, bs0.z, bs0.w};
    const float bb1[4] = {bs1.x, bs1.y, bs1.z, bs1.w};
#pragma unroll
    for (int i = 0; i < 8; ++i) {
        const int row = bm + ((i < 4) ? ((ty << 2) + i) : (64 + (ty << 2) + (i - 4)));
        float4 v0, v1;
        v0.x = acc[i][0] + bb0[0]; v0.y = acc[i][1] + bb0[1];
        v0.z = acc[i][2] + bb0[2]; v0.w = acc[i][3] + bb0[3];
        v1.x = acc[i][4] + bb1[0]; v1.y = acc[i][5] + bb1[1];
        v1.z = acc[i][6] + bb1[2]; v1.w = acc[i][7] + bb1[3];
        *(float4*)&C[(size_t)row * N + bn + (tx << 2)]      = v0;
        *(float4*)&C[(size_t)row * N + bn + 64 + (tx << 2)] = v1;
    }
}

// ===================== flash-style attention, fp32 =====================
// Block: 32 q-rows x one head x one batch. s-tiles of 64 (causal part skips
// fully-invisible tiles; memory-bank part unmasked). K stored transposed in
// LDS (Kst[d][s], stride 72); V reuses the same buffer (Vs[s][d], stride 136)
// after the score phase. Thread (rg,cg): 2 q-rows x 4 score cols; PV output
// d = 4*cg + {0..3} and 64 + 4*cg + {0..3} (interleaved -> conflict-free).
__global__ __launch_bounds__(256, 2)
void attn_kernel(const float* __restrict__ qkv, const float* __restrict__ mem,
                 float* __restrict__ attn_out)
{
    __shared__ float Qs[32][132];    // 16896 B
    __shared__ float KV[128 * 72];   // 36864 B: Kst[128][72] OR Vs[64][136]
    __shared__ float Ps[32][68];     //  8704 B   (total 62464 <= 64K)

    const int tid = threadIdx.x;
    const int qt = (int)gridDim.x - 1 - (int)blockIdx.x;  // heavy tiles first
    const int h = blockIdx.y, b = blockIdx.z;
    const int t0 = qt << 5;
    const int bT = b * T_SEQ;

    const int cg = tid & 15;
    const int rg = tid >> 4;
    const int r0 = rg << 1;

    // ---- load Q tile, pre-scaled by 1/sqrt(D) ----
    {
        const int r = tid >> 3, dq = (tid & 7) << 4;
        const float* qp = qkv + (size_t)(bT + t0 + r) * QKV_N + h * D_HEAD + dq;
        const float sc = 0.08838834764831845f;  // 1/sqrt(128)
#pragma unroll
        for (int i = 0; i < 4; ++i) {
            float4 v = *(const float4*)(qp + (i << 2));
            v.x *= sc; v.y *= sc; v.z *= sc; v.w *= sc;
            *(float4*)&Qs[r][dq + (i << 2)] = v;
        }
    }
    __syncthreads();

    float O[2][8];
#pragma unroll
    for (int rr = 0; rr < 2; ++rr)
#pragma unroll
        for (int i = 0; i < 8; ++i) O[rr][i] = 0.f;
    // -1e30 sentinel (finite: avoids inf-inf NaN; every row's first tile has
    // at least one visible col given QT=32/ST=64 with t0 multiple of 32)
    float m_i[2] = {-1e30f, -1e30f};
    float l_i[2] = {0.f, 0.f};

    const int nk = (t0 + 95) >> 6;          // causal-part s-tiles
    const int nt = nk + (MEM_N >> 6);       // + 16 memory tiles

    const int sl = tid >> 2, t4 = tid & 3;  // K/V loader mapping

    for (int it = 0; it < nt; ++it) {
        const bool ismem = (it >= nk);
        const int s0 = ismem ? (T_SEQ + ((it - nk) << 6)) : (it << 6);
        const float* kbase;
        int rstr;
        if (ismem) { kbase = mem + (size_t)(s0 - T_SEQ) * C_DIM + h * D_HEAD; rstr = C_DIM; }
        else       { kbase = qkv + (size_t)(bT + s0) * QKV_N + C_DIM + h * D_HEAD; rstr = QKV_N; }

        // prefetch K tile to regs (d = t4 + 4i : odd-bank transpose store)
        float kreg[32];
        {
            const float* kp = kbase + (size_t)sl * rstr + t4;
#pragma unroll
            for (int i = 0; i < 32; ++i) kreg[i] = kp[i << 2];
        }
        __syncthreads();   // previous PV done with KV
#pragma unroll
        for (int i = 0; i < 32; ++i) KV[(t4 + (i << 2)) * 72 + sl] = kreg[i];
        __syncthreads();   // Kst ready

        // prefetch V tile during score phase
        float4 vreg[8];
        {
            const float* vp = kbase + (ismem ? 0 : C_DIM) + (size_t)sl * rstr + (t4 << 2);
#pragma unroll
            for (int i = 0; i < 8; ++i) vreg[i] = *(const float4*)(vp + (i << 4));
        }

        // ---- scores: 2 rows x 4 cols per thread ----
        float s0v[4] = {0.f, 0.f, 0.f, 0.f}, s1v[4] = {0.f, 0.f, 0.f, 0.f};
#pragma unroll 4
        for (int k = 0; k < 128; k += 4) {
            const float4 q0 = *(const float4*)&Qs[r0][k];
            const float4 q1 = *(const float4*)&Qs[r0 + 1][k];
            const float qa[4] = {q0.x, q0.y, q0.z, q0.w};
            const float qb[4] = {q1.x, q1.y, q1.z, q1.w};
#pragma unroll
            for (int kk = 0; kk < 4; ++kk) {
                const float4 kv = *(const float4*)&KV[(k + kk) * 72 + (cg << 2)];
                const float kvv[4] = {kv.x, kv.y, kv.z, kv.w};
#pragma unroll
                for (int j = 0; j < 4; ++j) {
                    s0v[j] = fmaf(qa[kk], kvv[j], s0v[j]);
                    s1v[j] = fmaf(qb[kk], kvv[j], s1v[j]);
                }
            }
        }

        if (!ismem && (s0 + 63 > t0)) {     // only boundary tiles mask
#pragma unroll
            for (int j = 0; j < 4; ++j) {
                const int s = s0 + (cg << 2) + j;
                if (s > t0 + r0)     s0v[j] = -1e30f;
                if (s > t0 + r0 + 1) s1v[j] = -1e30f;
            }
        }

        // ---- online softmax (16-lane shuffle reductions) ----
        float mx0 = fmaxf(fmaxf(s0v[0], s0v[1]), fmaxf(s0v[2], s0v[3]));
        float mx1 = fmaxf(fmaxf(s1v[0], s1v[1]), fmaxf(s1v[2], s1v[3]));
#pragma unroll
        for (int off = 1; off < 16; off <<= 1) {
            mx0 = fmaxf(mx0, __shfl_xor(mx0, off));
            mx1 = fmaxf(mx1, __shfl_xor(mx1, off));
        }
        const float mn0 = fmaxf(m_i[0], mx0), mn1 = fmaxf(m_i[1], mx1);
        const float al0 = __expf(m_i[0] - mn0), al1 = __expf(m_i[1] - mn1);
        float p0[4], p1[4], ps0 = 0.f, ps1 = 0.f;
#pragma unroll
        for (int j = 0; j < 4; ++j) {
            p0[j] = __expf(s0v[j] - mn0); ps0 += p0[j];
            p1[j] = __expf(s1v[j] - mn1); ps1 += p1[j];
        }
#pragma unroll
        for (int off = 1; off < 16; off <<= 1) {
            ps0 += __shfl_xor(ps0, off);
            ps1 += __shfl_xor(ps1, off);
        }
        l_i[0] = l_i[0] * al0 + ps0;
        l_i[1] = l_i[1] * al1 + ps1;
        m_i[0] = mn0; m_i[1] = mn1;
#pragma unroll
        for (int i = 0; i < 8; ++i) { O[0][i] *= al0; O[1][i] *= al1; }
        float4 pw0, pw1;
        pw0.x = p0[0]; pw0.y = p0[1]; pw0.z = p0[2]; pw0.w = p0[3];
        pw1.x = p1[0]; pw1.y = p1[1]; pw1.z = p1[2]; pw1.w = p1[3];
        *(float4*)&Ps[r0][cg << 2]     = pw0;
        *(float4*)&Ps[r0 + 1][cg << 2] = pw1;

        __syncthreads();   // score phase done reading KV; Ps written
        {
            const int vr = sl;
#pragma unroll
            for (int i = 0; i < 8; ++i)
                *(float4*)&KV[vr * 136 + (t4 << 2) + (i << 4)] = vreg[i];
        }
        __syncthreads();   // Vs + Ps visible

        // ---- PV: O[r][d] += sum_c P[r][c] * V[c][d] ----
#pragma unroll 4
        for (int c = 0; c < 64; ++c) {
            const float pa = Ps[r0][c], pb = Ps[r0 + 1][c];
            const float4 v0 = *(const float4*)&KV[c * 136 + (cg << 2)];
            const float4 v1 = *(const float4*)&KV[c * 136 + 64 + (cg << 2)];
            const float va[4] = {v0.x, v0.y, v0.z, v0.w};
            const float vb[4] = {v1.x, v1.y, v1.z, v1.w};
#pragma unroll
            for (int j = 0; j < 4; ++j) {
                O[0][j]     = fmaf(pa, va[j], O[0][j]);
                O[0][4 + j] = fmaf(pa, vb[j], O[0][4 + j]);
                O[1][j]     = fmaf(pb, va[j], O[1][j]);
                O[1][4 + j] = fmaf(pb, vb[j], O[1][4 + j]);
            }
        }
    }

    // ---- normalize + write ----
    const float inv0 = 1.f / l_i[0], inv1 = 1.f / l_i[1];
    float* op0 = attn_out + (size_t)(bT + t0 + r0) * C_DIM + h * D_HEAD + (cg << 2);
    float* op1 = op0 + C_DIM;
    float4 w;
    w.x = O[0][0] * inv0; w.y = O[0][1] * inv0; w.z = O[0][2] * inv0; w.w = O[0][3] * inv0;
    *(float4*)op0 = w;
    w.x = O[0][4] * inv0; w.y = O[0][5] * inv0; w.z = O[0][6] * inv0; w.w = O[0][7] * inv0;
    *(float4*)(op0 + 64) = w;
    w.x = O[1][0] * inv1; w.y = O[1][1] * inv1; w.z = O[1][2] * inv1; w.w = O[1][3] * inv1;
    *(float4*)op1 = w;
    w.x = O[1][4] * inv1; w.y = O[1][5] * inv1; w.z = O[1][6] * inv1; w.w = O[1][7] * inv1;
    *(float4*)(op1 + 64) = w;
}

extern "C" void kernel_launch(void* const* d_in, const int* in_sizes, int n_in,
                              void* d_out, int out_size, void* d_ws, size_t ws_size,
                              hipStream_t stream)
{
    const float* x     = (const float*)d_in[0];
    const float* Wqkv  = (const float*)d_in[1];
    const float* bqkv  = (const float*)d_in[2];
    const float* mem   = (const float*)d_in[3];
    const float* Wproj = (const float*)d_in[4];
    const float* bproj = (const float*)d_in[5];
    float* out = (float*)d_out;

    float* qkv  = (float*)d_ws;                    // [4096, 6144]  (96 MB)
    float* attn = qkv + (size_t)4096 * QKV_N;      // [4096, 2048]  (32 MB)

    // 1) QKV projection: [4096,2048] @ [2048,6144] + b
    dim3 g1(QKV_N / 128, 4096 / 128);
    gemm_bias_kernel<<<g1, 256, 0, stream>>>(x, Wqkv, bqkv, qkv, 4096, QKV_N, 2048);

    // 2) attention (causal over T, memory bank fully visible)
    dim3 g2(T_SEQ / 32, H_NUM, 2);
    attn_kernel<<<g2, 256, 0, stream>>>(qkv, mem, attn);

    // 3) output projection: [4096,2048] @ [2048,2048] + b
    dim3 g3(C_DIM / 128, 4096 / 128);
    gemm_bias_kernel<<<g3, 256, 0, stream>>>(attn, Wproj, bproj, out, 4096, C_DIM, 2048);
}

// Round 2
// 2161.426 us; speedup vs baseline: 1.6047x; 1.6047x over previous
//
#include <hip/hip_runtime.h>
#include <math.h>

#define T_SEQ  2048
#define C_DIM  2048
#define H_NUM  16
#define D_HEAD 128
#define MEM_N  1024
#define S_ALL  3072   // T + MEM
#define QKV_N  6144   // 3*C

typedef __attribute__((ext_vector_type(4))) float f32x4;
typedef __attribute__((ext_vector_type(8))) short bf16x8;
typedef __attribute__((ext_vector_type(8))) unsigned short us8;

__device__ __forceinline__ unsigned short f2bf(float f) {
    unsigned int u = __float_as_uint(f);
    u = (u + 0x7fffu + ((u >> 16) & 1u)) >> 16;   // RNE
    return (unsigned short)u;
}

// ================= GEMM fp32 out (proj): C = A@B + bias =================
__global__ __launch_bounds__(256, 2)
void gemm_bias_kernel(const float* __restrict__ A, const float* __restrict__ B,
                      const float* __restrict__ bias, float* __restrict__ C,
                      int M, int N, int K)
{
    __shared__ float As[16][132];
    __shared__ float Bs[16][132];

    const int tid = threadIdx.x;
    const int tx = tid & 15, ty = tid >> 4;
    const int bm = blockIdx.y * 128, bn = blockIdx.x * 128;

    const int lar = tid >> 2;
    const int lak = (tid & 3) << 2;
    const int lbk = tid >> 4;
    const int lbn = (tid & 15) << 3;

    const float* pA0 = A + (size_t)(bm + lar) * K + lak;
    const float* pA1 = A + (size_t)(bm + 64 + lar) * K + lak;
    const float* pB  = B + (size_t)lbk * N + bn + lbn;

    float acc[8][8];
#pragma unroll
    for (int i = 0; i < 8; ++i)
#pragma unroll
        for (int j = 0; j < 8; ++j) acc[i][j] = 0.f;

    for (int kt = 0; kt < K; kt += 16) {
        const float4 a0 = *(const float4*)(pA0 + kt);
        const float4 a1 = *(const float4*)(pA1 + kt);
        const float4 b0 = *(const float4*)(pB + (size_t)kt * N);
        const float4 b1 = *(const float4*)(pB + (size_t)kt * N + 4);
        __syncthreads();
        As[lak + 0][lar] = a0.x; As[lak + 1][lar] = a0.y;
        As[lak + 2][lar] = a0.z; As[lak + 3][lar] = a0.w;
        As[lak + 0][64 + lar] = a1.x; As[lak + 1][64 + lar] = a1.y;
        As[lak + 2][64 + lar] = a1.z; As[lak + 3][64 + lar] = a1.w;
        *(float4*)&Bs[lbk][lbn]     = b0;
        *(float4*)&Bs[lbk][lbn + 4] = b1;
        __syncthreads();
#pragma unroll
        for (int kk = 0; kk < 16; ++kk) {
            const float4 av0 = *(const float4*)&As[kk][ty << 2];
            const float4 av1 = *(const float4*)&As[kk][64 + (ty << 2)];
            const float4 bv0 = *(const float4*)&Bs[kk][tx << 2];
            const float4 bv1 = *(const float4*)&Bs[kk][64 + (tx << 2)];
            const float a[8]  = {av0.x, av0.y, av0.z, av0.w, av1.x, av1.y, av1.z, av1.w};
            const float bb[8] = {bv0.x, bv0.y, bv0.z, bv0.w, bv1.x, bv1.y, bv1.z, bv1.w};
#pragma unroll
            for (int i = 0; i < 8; ++i)
#pragma unroll
                for (int j = 0; j < 8; ++j)
                    acc[i][j] = fmaf(a[i], bb[j], acc[i][j]);
        }
    }

    const float4 bs0 = *(const float4*)&bias[bn + (tx << 2)];
    const float4 bs1 = *(const float4*)&bias[bn + 64 + (tx << 2)];
    const float bb0[4] = {bs0.x, bs0.y, bs0.z, bs0.w};
    const float bb1[4] = {bs1.x, bs1.y, bs1.z, bs1.w};
#pragma unroll
    for (int i = 0; i < 8; ++i) {
        const int row = bm + ((i < 4) ? ((ty << 2) + i) : (64 + (ty << 2) + (i - 4)));
        float4 v0, v1;
        v0.x = acc[i][0] + bb0[0]; v0.y = acc[i][1] + bb0[1];
        v0.z = acc[i][2] + bb0[2]; v0.w = acc[i][3] + bb0[3];
        v1.x = acc[i][4] + bb1[0]; v1.y = acc[i][5] + bb1[1];
        v1.z = acc[i][6] + bb1[2]; v1.w = acc[i][7] + bb1[3];
        *(float4*)&C[(size_t)row * N + bn + (tx << 2)]      = v0;
        *(float4*)&C[(size_t)row * N + bn + 64 + (tx << 2)] = v1;
    }
}

// ================= GEMM bf16 out (QKV): C = bf16((A@B + bias)*scl) =========
// scl applied to columns < scale_cols (pre-scales Q by 1/sqrt(D)).
__global__ __launch_bounds__(256, 2)
void gemm_bias_bf16_kernel(const float* __restrict__ A, const float* __restrict__ B,
                           const float* __restrict__ bias, unsigned short* __restrict__ C,
                           int M, int N, int K, int scale_cols, float scale_val)
{
    __shared__ float As[16][132];
    __shared__ float Bs[16][132];

    const int tid = threadIdx.x;
    const int tx = tid & 15, ty = tid >> 4;
    const int bm = blockIdx.y * 128, bn = blockIdx.x * 128;

    const int lar = tid >> 2;
    const int lak = (tid & 3) << 2;
    const int lbk = tid >> 4;
    const int lbn = (tid & 15) << 3;

    const float* pA0 = A + (size_t)(bm + lar) * K + lak;
    const float* pA1 = A + (size_t)(bm + 64 + lar) * K + lak;
    const float* pB  = B + (size_t)lbk * N + bn + lbn;

    float acc[8][8];
#pragma unroll
    for (int i = 0; i < 8; ++i)
#pragma unroll
        for (int j = 0; j < 8; ++j) acc[i][j] = 0.f;

    for (int kt = 0; kt < K; kt += 16) {
        const float4 a0 = *(const float4*)(pA0 + kt);
        const float4 a1 = *(const float4*)(pA1 + kt);
        const float4 b0 = *(const float4*)(pB + (size_t)kt * N);
        const float4 b1 = *(const float4*)(pB + (size_t)kt * N + 4);
        __syncthreads();
        As[lak + 0][lar] = a0.x; As[lak + 1][lar] = a0.y;
        As[lak + 2][lar] = a0.z; As[lak + 3][lar] = a0.w;
        As[lak + 0][64 + lar] = a1.x; As[lak + 1][64 + lar] = a1.y;
        As[lak + 2][64 + lar] = a1.z; As[lak + 3][64 + lar] = a1.w;
        *(float4*)&Bs[lbk][lbn]     = b0;
        *(float4*)&Bs[lbk][lbn + 4] = b1;
        __syncthreads();
#pragma unroll
        for (int kk = 0; kk < 16; ++kk) {
            const float4 av0 = *(const float4*)&As[kk][ty << 2];
            const float4 av1 = *(const float4*)&As[kk][64 + (ty << 2)];
            const float4 bv0 = *(const float4*)&Bs[kk][tx << 2];
            const float4 bv1 = *(const float4*)&Bs[kk][64 + (tx << 2)];
            const float a[8]  = {av0.x, av0.y, av0.z, av0.w, av1.x, av1.y, av1.z, av1.w};
            const float bb[8] = {bv0.x, bv0.y, bv0.z, bv0.w, bv1.x, bv1.y, bv1.z, bv1.w};
#pragma unroll
            for (int i = 0; i < 8; ++i)
#pragma unroll
                for (int j = 0; j < 8; ++j)
                    acc[i][j] = fmaf(a[i], bb[j], acc[i][j]);
        }
    }

    const float scl = (bn < scale_cols) ? scale_val : 1.0f;  // 128-col block uniform
    const float4 bs0 = *(const float4*)&bias[bn + (tx << 2)];
    const float4 bs1 = *(const float4*)&bias[bn + 64 + (tx << 2)];
    const float bb0[4] = {bs0.x, bs0.y, bs0.z, bs0.w};
    const float bb1[4] = {bs1.x, bs1.y, bs1.z, bs1.w};
#pragma unroll
    for (int i = 0; i < 8; ++i) {
        const int row = bm + ((i < 4) ? ((ty << 2) + i) : (64 + (ty << 2) + (i - 4)));
        ushort4 o0, o1;
        o0.x = f2bf((acc[i][0] + bb0[0]) * scl); o0.y = f2bf((acc[i][1] + bb0[1]) * scl);
        o0.z = f2bf((acc[i][2] + bb0[2]) * scl); o0.w = f2bf((acc[i][3] + bb0[3]) * scl);
        o1.x = f2bf((acc[i][4] + bb1[0]) * scl); o1.y = f2bf((acc[i][5] + bb1[1]) * scl);
        o1.z = f2bf((acc[i][6] + bb1[2]) * scl); o1.w = f2bf((acc[i][7] + bb1[3]) * scl);
        *(ushort4*)&C[(size_t)row * N + bn + (tx << 2)]      = o0;
        *(ushort4*)&C[(size_t)row * N + bn + 64 + (tx << 2)] = o1;
    }
}

// ====== prep: build K[b,h,3072,128] bf16 and Vt[b,h,128,3072] bf16 ======
// s<2048 from bf16 qkv (K,V parts); s>=2048 from fp32 memory bank (K=V=mem).
__global__ __launch_bounds__(256, 2)
void prep_kv_kernel(const unsigned short* __restrict__ qkv, const float* __restrict__ mem,
                    unsigned short* __restrict__ Kall, unsigned short* __restrict__ Vtall)
{
    __shared__ unsigned short Vtmp[64 * 136];

    const int tid = threadIdx.x;
    const int s0 = (int)blockIdx.x << 6;          // 0..3071 in steps of 64
    const int h = blockIdx.y, b = blockIdx.z;
    const int bh = b * H_NUM + h;

    const int sr = tid >> 2, ch = (tid & 3) << 5; // 32-element chunk
    const int s = s0 + sr;

    us8 kq[4], vq[4];
    if (s0 < T_SEQ) {
        const unsigned short* kp = qkv + (size_t)(b * T_SEQ + s) * QKV_N + C_DIM + h * D_HEAD + ch;
        const unsigned short* vp = kp + C_DIM;
#pragma unroll
        for (int i = 0; i < 4; ++i) {
            kq[i] = *(const us8*)(kp + (i << 3));
            vq[i] = *(const us8*)(vp + (i << 3));
        }
    } else {
        const float* mp = mem + (size_t)(s - T_SEQ) * C_DIM + h * D_HEAD + ch;
#pragma unroll
        for (int i = 0; i < 4; ++i) {
            const float4 f0 = *(const float4*)(mp + (i << 3));
            const float4 f1 = *(const float4*)(mp + (i << 3) + 4);
            us8 r;
            r[0] = f2bf(f0.x); r[1] = f2bf(f0.y); r[2] = f2bf(f0.z); r[3] = f2bf(f0.w);
            r[4] = f2bf(f1.x); r[5] = f2bf(f1.y); r[6] = f2bf(f1.z); r[7] = f2bf(f1.w);
            kq[i] = r; vq[i] = r;
        }
    }

    unsigned short* kd = Kall + (size_t)bh * S_ALL * D_HEAD + (size_t)s * D_HEAD + ch;
#pragma unroll
    for (int i = 0; i < 4; ++i) {
        *(us8*)(kd + (i << 3)) = kq[i];
        *(us8*)&Vtmp[sr * 136 + ch + (i << 3)] = vq[i];
    }
    __syncthreads();

    // transpose 64x128 -> Vt rows (d-major)
    const int d = tid >> 1, half = tid & 1;
    unsigned short* vd = Vtall + (size_t)bh * D_HEAD * S_ALL + (size_t)d * S_ALL + s0 + half * 32;
#pragma unroll
    for (int c = 0; c < 4; ++c) {
        us8 o;
#pragma unroll
        for (int j = 0; j < 8; ++j)
            o[j] = Vtmp[(half * 32 + (c << 3) + j) * 136 + d];
        *(us8*)(vd + (c << 3)) = o;
    }
}

// ===================== MFMA flash attention (bf16 in, fp32 out) =============
// Block: 64 q-rows x one (h,b). 4 waves, wave w owns q-rows [16w,16w+16).
// s-tiles of 64: QK^T via 16x16x32 bf16 MFMA (Q pre-scaled), online softmax in
// C-layout (col=lane&15, row=quad*4+reg), P round-trips through LDS (aliased
// into K buffer) to A-layout, PV via MFMA into 8x f32x4 accumulators.
__global__ __launch_bounds__(256, 3)
void attn_mfma_kernel(const unsigned short* __restrict__ qkv,
                      const unsigned short* __restrict__ Kall,
                      const unsigned short* __restrict__ Vtall,
                      float* __restrict__ attn_out)
{
    __shared__ unsigned short Qs[64 * 136];   // 17408 B  (272B row = 17x16 odd)
    __shared__ unsigned short Ks[64 * 136];   // 17408 B; aliased as Ps[64*72]
    __shared__ unsigned short Vts[128 * 72];  // 18432 B  (144B row = 9x16 odd)
    unsigned short* Ps = Ks;                  // total 53248 B -> 3 blocks/CU

    const int tid = threadIdx.x;
    const int w = tid >> 6, lane = tid & 63;
    const int c16 = lane & 15, quad = lane >> 4;
    const int qt = (int)gridDim.x - 1 - (int)blockIdx.x;  // heavy tiles first
    const int h = blockIdx.y, b = blockIdx.z;
    const int t0 = qt << 6;
    const int bT = b * T_SEQ;
    const int bh = b * H_NUM + h;

    const unsigned short* Kbase = Kall + (size_t)bh * S_ALL * D_HEAD;
    const unsigned short* Vbase = Vtall + (size_t)bh * D_HEAD * S_ALL;

    // ---- stage Q tile (bf16, pre-scaled by 1/sqrt(D) in GEMM1) ----
    {
        const int r = tid >> 2, ch = (tid & 3) << 5;
        const unsigned short* src = qkv + (size_t)(bT + t0 + r) * QKV_N + h * D_HEAD + ch;
#pragma unroll
        for (int i = 0; i < 4; ++i)
            *(float4*)&Qs[r * 136 + ch + (i << 3)] = *(const float4*)(src + (i << 3));
    }

    f32x4 acc_o[8];
#pragma unroll
    for (int i = 0; i < 8; ++i) acc_o[i] = (f32x4){0.f, 0.f, 0.f, 0.f};
    float m_r[4] = {-1e30f, -1e30f, -1e30f, -1e30f};
    float l_r[4] = {0.f, 0.f, 0.f, 0.f};

    const int nk = qt + 1;                 // causal s-tiles
    const int ntile = nk + (MEM_N >> 6);   // + memory tiles

    const int sK = tid >> 2, cK = (tid & 3) << 5;   // K-tile loader
    const int dV = tid >> 1, cV = (tid & 1) << 5;   // Vt-tile loader

    // prefetch tile 0
    float4 kf[4], vf[4];
    {
        const unsigned short* kp = Kbase + (size_t)sK * D_HEAD + cK;
        const unsigned short* vp = Vbase + (size_t)dV * S_ALL + cV;
#pragma unroll
        for (int i = 0; i < 4; ++i) {
            kf[i] = *(const float4*)(kp + (i << 3));
            vf[i] = *(const float4*)(vp + (i << 3));
        }
    }

    for (int it = 0; it < ntile; ++it) {
        __syncthreads();   // previous PV done reading Vts/Ps
#pragma unroll
        for (int i = 0; i < 4; ++i) {
            *(float4*)&Ks[sK * 136 + cK + (i << 3)] = kf[i];
            *(float4*)&Vts[dV * 72 + cV + (i << 3)] = vf[i];
        }
        if (it + 1 < ntile) {   // prefetch next tile while computing
            const int s0n = (it + 1 < nk) ? ((it + 1) << 6) : (T_SEQ + ((it + 1 - nk) << 6));
            const unsigned short* kp = Kbase + (size_t)(s0n + sK) * D_HEAD + cK;
            const unsigned short* vp = Vbase + (size_t)dV * S_ALL + s0n + cV;
#pragma unroll
            for (int i = 0; i < 4; ++i) {
                kf[i] = *(const float4*)(kp + (i << 3));
                vf[i] = *(const float4*)(vp + (i << 3));
            }
        }
        __syncthreads();   // K/Vt (and Q on it=0) staged

        // ---- QK^T: 4 n-tiles x 4 k-steps ----
        f32x4 acc_s[4];
#pragma unroll
        for (int i = 0; i < 4; ++i) acc_s[i] = (f32x4){0.f, 0.f, 0.f, 0.f};
#pragma unroll
        for (int kk = 0; kk < 4; ++kk) {
            const bf16x8 a = *(const bf16x8*)&Qs[(w * 16 + c16) * 136 + (kk << 5) + (quad << 3)];
#pragma unroll
            for (int nt = 0; nt < 4; ++nt) {
                const bf16x8 bb = *(const bf16x8*)&Ks[(nt * 16 + c16) * 136 + (kk << 5) + (quad << 3)];
                acc_s[nt] = __builtin_amdgcn_mfma_f32_16x16x32_bf16(a, bb, acc_s[nt], 0, 0, 0);
            }
        }

        float sv[4][4];
#pragma unroll
        for (int nt = 0; nt < 4; ++nt)
#pragma unroll
            for (int r = 0; r < 4; ++r) sv[nt][r] = acc_s[nt][r];

        if (it == nk - 1) {   // diagonal tile: s0 == t0, only tile needing mask
#pragma unroll
            for (int nt = 0; nt < 4; ++nt) {
                const int scol = t0 + nt * 16 + c16;
#pragma unroll
                for (int r = 0; r < 4; ++r) {
                    const int trow = t0 + w * 16 + quad * 4 + r;
                    if (scol > trow) sv[nt][r] = -1e30f;
                }
            }
        }

        // ---- online softmax (rows live in quad-groups; 16-lane reductions) ----
        float mx[4], mn[4], al[4], rs[4], p[4][4];
#pragma unroll
        for (int r = 0; r < 4; ++r)
            mx[r] = fmaxf(fmaxf(sv[0][r], sv[1][r]), fmaxf(sv[2][r], sv[3][r]));
#pragma unroll
        for (int off = 1; off < 16; off <<= 1)
#pragma unroll
            for (int r = 0; r < 4; ++r) mx[r] = fmaxf(mx[r], __shfl_xor(mx[r], off));
#pragma unroll
        for (int r = 0; r < 4; ++r) {
            mn[r] = fmaxf(m_r[r], mx[r]);
            al[r] = __expf(m_r[r] - mn[r]);
            m_r[r] = mn[r];
        }
#pragma unroll
        for (int nt = 0; nt < 4; ++nt)
#pragma unroll
            for (int r = 0; r < 4; ++r) p[nt][r] = __expf(sv[nt][r] - mn[r]);
#pragma unroll
        for (int r = 0; r < 4; ++r) rs[r] = (p[0][r] + p[1][r]) + (p[2][r] + p[3][r]);
#pragma unroll
        for (int off = 1; off < 16; off <<= 1)
#pragma unroll
            for (int r = 0; r < 4; ++r) rs[r] += __shfl_xor(rs[r], off);
#pragma unroll
        for (int r = 0; r < 4; ++r) l_r[r] = l_r[r] * al[r] + rs[r];
#pragma unroll
        for (int nt = 0; nt < 8; ++nt)
#pragma unroll
            for (int r = 0; r < 4; ++r) acc_o[nt][r] *= al[r];

        __syncthreads();   // all QK reads of Ks done -> safe to overwrite as Ps
#pragma unroll
        for (int nt = 0; nt < 4; ++nt)
#pragma unroll
            for (int r = 0; r < 4; ++r)
                Ps[(w * 16 + quad * 4 + r) * 72 + nt * 16 + c16] = f2bf(p[nt][r]);
        __syncthreads();   // Ps visible

        // ---- PV: 8 d-tiles x 2 k-steps ----
#pragma unroll
        for (int ks = 0; ks < 2; ++ks) {
            const bf16x8 a = *(const bf16x8*)&Ps[(w * 16 + c16) * 72 + (ks << 5) + (quad << 3)];
#pragma unroll
            for (int nt = 0; nt < 8; ++nt) {
                const bf16x8 bb = *(const bf16x8*)&Vts[(nt * 16 + c16) * 72 + (ks << 5) + (quad << 3)];
                acc_o[nt] = __builtin_amdgcn_mfma_f32_16x16x32_bf16(a, bb, acc_o[nt], 0, 0, 0);
            }
        }
    }

    // ---- normalize + write (fp32) ----
    float inv[4];
#pragma unroll
    for (int r = 0; r < 4; ++r) inv[r] = 1.0f / l_r[r];
#pragma unroll
    for (int r = 0; r < 4; ++r) {
        float* op = attn_out + (size_t)(bT + t0 + w * 16 + quad * 4 + r) * C_DIM + h * D_HEAD + c16;
#pragma unroll
        for (int nt = 0; nt < 8; ++nt)
            op[nt * 16] = acc_o[nt][r] * inv[r];
    }
}

extern "C" void kernel_launch(void* const* d_in, const int* in_sizes, int n_in,
                              void* d_out, int out_size, void* d_ws, size_t ws_size,
                              hipStream_t stream)
{
    const float* x     = (const float*)d_in[0];
    const float* Wqkv  = (const float*)d_in[1];
    const float* bqkv  = (const float*)d_in[2];
    const float* mem   = (const float*)d_in[3];
    const float* Wproj = (const float*)d_in[4];
    const float* bproj = (const float*)d_in[5];
    float* out = (float*)d_out;

    // workspace: attn fp32 (32MB) | qkv bf16 (48MB) | Kall (24MB) | Vtall (24MB)
    float* attn = (float*)d_ws;
    unsigned short* qkvb  = (unsigned short*)(attn + (size_t)4096 * C_DIM);
    unsigned short* Kall  = qkvb + (size_t)4096 * QKV_N;
    unsigned short* Vtall = Kall + (size_t)2 * H_NUM * S_ALL * D_HEAD;

    // 1) QKV projection -> bf16, Q pre-scaled by 1/sqrt(128)
    dim3 g1(QKV_N / 128, 4096 / 128);
    gemm_bias_bf16_kernel<<<g1, 256, 0, stream>>>(x, Wqkv, bqkv, qkvb, 4096, QKV_N, 2048,
                                                  C_DIM, 0.08838834764831845f);

    // 2) build unified K / transposed V (memory bank folded in)
    dim3 g2(S_ALL / 64, H_NUM, 2);
    prep_kv_kernel<<<g2, 256, 0, stream>>>(qkvb, mem, Kall, Vtall);

    // 3) MFMA flash attention
    dim3 g3(T_SEQ / 64, H_NUM, 2);
    attn_mfma_kernel<<<g3, 256, 0, stream>>>(qkvb, Kall, Vtall, attn);

    // 4) output projection (fp32)
    dim3 g4(C_DIM / 128, 4096 / 128);
    gemm_bias_kernel<<<g4, 256, 0, stream>>>(attn, Wproj, bproj, out, 4096, C_DIM, 2048);
}

// Round 3
// 1090.118 us; speedup vs baseline: 3.1818x; 1.9827x over previous
//
#include <hip/hip_runtime.h>
#include <math.h>

#define T_SEQ  2048
#define C_DIM  2048
#define H_NUM  16
#define D_HEAD 128
#define MEM_N  1024
#define S_ALL  3072
#define QKV_N  6144

typedef __attribute__((ext_vector_type(4))) float f32x4;
typedef __attribute__((ext_vector_type(8))) short bf16x8;
typedef __attribute__((ext_vector_type(8))) unsigned short us8;

__device__ __forceinline__ unsigned short f2bf(float f) {
    unsigned int u = __float_as_uint(f);
    u = (u + 0x7fffu + ((u >> 16) & 1u)) >> 16;   // RNE
    return (unsigned short)u;
}

// async global->LDS, 16B per lane; lds ptr must be wave-uniform (HW adds lane*16)
__device__ __forceinline__ void gload_lds16(const void* g, void* l) {
    __builtin_amdgcn_global_load_lds((const __attribute__((address_space(1))) void*)g,
                                     (__attribute__((address_space(3))) void*)l, 16, 0, 0);
}

// ===== split+transpose W: [K=2048, N] fp32 -> Th/Tl [N][2048] bf16 (hi/lo) =====
__global__ __launch_bounds__(256, 2)
void split_w_t(const float* __restrict__ W, unsigned short* __restrict__ Th,
               unsigned short* __restrict__ Tl, int N)
{
    __shared__ float tile[64][68];
    const int tid = threadIdx.x;
    const int n0 = blockIdx.x << 6, k0 = blockIdx.y << 6;
    const int r = tid >> 2, c4 = (tid & 3) << 4;
    const float* src = W + (size_t)(k0 + r) * N + n0 + c4;
#pragma unroll
    for (int i = 0; i < 4; ++i)
        *(float4*)&tile[r][c4 + (i << 2)] = *(const float4*)(src + (i << 2));
    __syncthreads();
    unsigned int hi[8], lo[8];
#pragma unroll
    for (int e = 0; e < 8; ++e) {
        const float f0 = tile[c4 + 2 * e][r], f1 = tile[c4 + 2 * e + 1][r];
        const unsigned int u0 = __float_as_uint(f0), u1 = __float_as_uint(f1);
        const float l0 = f0 - __uint_as_float(u0 & 0xFFFF0000u);
        const float l1 = f1 - __uint_as_float(u1 & 0xFFFF0000u);
        hi[e] = (u0 >> 16) | (u1 & 0xFFFF0000u);
        lo[e] = (__float_as_uint(l0) >> 16) | (__float_as_uint(l1) & 0xFFFF0000u);
    }
    unsigned short* dh = Th + (size_t)(n0 + r) * 2048 + k0 + c4;
    unsigned short* dl = Tl + (size_t)(n0 + r) * 2048 + k0 + c4;
    *(uint4*)dh       = make_uint4(hi[0], hi[1], hi[2], hi[3]);
    *(uint4*)(dh + 8) = make_uint4(hi[4], hi[5], hi[6], hi[7]);
    *(uint4*)dl       = make_uint4(lo[0], lo[1], lo[2], lo[3]);
    *(uint4*)(dl + 8) = make_uint4(lo[4], lo[5], lo[6], lo[7]);
}

// ===== memory bank: fp32 [1024,2048] -> memb bf16 [1024,2048] + memt bf16 [2048,1024]
__global__ __launch_bounds__(256, 2)
void split_mem_kernel(const float* __restrict__ mem, unsigned short* __restrict__ memb,
                      unsigned short* __restrict__ memt)
{
    __shared__ float tile[64][68];
    const int tid = threadIdx.x;
    const int c0 = blockIdx.x << 6, s0 = blockIdx.y << 6;
    const int r = tid >> 2, c4 = (tid & 3) << 4;
    const float* src = mem + (size_t)(s0 + r) * 2048 + c0 + c4;
    unsigned short* db = memb + (size_t)(s0 + r) * 2048 + c0 + c4;
#pragma unroll
    for (int i = 0; i < 4; ++i) {
        const float4 v = *(const float4*)(src + (i << 2));
        *(float4*)&tile[r][c4 + (i << 2)] = v;
        ushort4 o;
        o.x = f2bf(v.x); o.y = f2bf(v.y); o.z = f2bf(v.z); o.w = f2bf(v.w);
        *(ushort4*)(db + (i << 2)) = o;
    }
    __syncthreads();
    unsigned short* dt = memt + (size_t)(c0 + r) * 1024 + s0 + c4;
#pragma unroll
    for (int i = 0; i < 4; ++i) {
        ushort4 o;
        o.x = f2bf(tile[c4 + (i << 2) + 0][r]);
        o.y = f2bf(tile[c4 + (i << 2) + 1][r]);
        o.z = f2bf(tile[c4 + (i << 2) + 2][r]);
        o.w = f2bf(tile[c4 + (i << 2) + 3][r]);
        *(ushort4*)(dt + (i << 2)) = o;
    }
}

// ===== Vr [b,h,2048,128] bf16 -> Vrt [b,h,128,2048] bf16 =====
__global__ __launch_bounds__(256, 2)
void transpose_v_kernel(const unsigned short* __restrict__ Vr, unsigned short* __restrict__ Vrt)
{
    __shared__ unsigned short Vtmp[64 * 136];
    const int tid = threadIdx.x;
    const int s0 = (int)blockIdx.x << 6;
    const int h = blockIdx.y, b = blockIdx.z;
    const size_t bho = (size_t)(b * H_NUM + h) * (2048 * 128);
    const int sr = tid >> 2, ch = (tid & 3) << 5;
    const unsigned short* vp = Vr + bho + (size_t)(s0 + sr) * 128 + ch;
#pragma unroll
    for (int i = 0; i < 4; ++i)
        *(float4*)&Vtmp[sr * 136 + ch + (i << 3)] = *(const float4*)(vp + (i << 3));
    __syncthreads();
    const int d = tid >> 1, half = tid & 1;
    unsigned short* vd = Vrt + bho + (size_t)d * 2048 + s0 + (half << 5);
#pragma unroll
    for (int c = 0; c < 4; ++c) {
        us8 o;
#pragma unroll
        for (int j = 0; j < 8; ++j)
            o[j] = Vtmp[((half << 5) + (c << 3) + j) * 136 + d];
        *(us8*)(vd + (c << 3)) = o;
    }
}

// ===== GEMM1: qkv = x @ WqT^T + b, hi/lo MFMA; scatter epilogue to qb/Kr/Vr =====
__global__ __launch_bounds__(256, 3)
void gemm_qkv_mfma(const float* __restrict__ x,
                   const unsigned short* __restrict__ Bth, const unsigned short* __restrict__ Btl,
                   const float* __restrict__ bias,
                   unsigned short* __restrict__ qb, unsigned short* __restrict__ Kr,
                   unsigned short* __restrict__ Vr)
{
    __shared__ unsigned short Ah[128 * 32], Al[128 * 32], Bh[128 * 32], Bl[128 * 32];
    const int tid = threadIdx.x;
    const int w = tid >> 6, lane = tid & 63, c16 = lane & 15, quad = lane >> 4;
    const int wm = w & 1, wn = w >> 1;
    const int bm = blockIdx.y << 7, bn = blockIdx.x << 7;

    const int ar = tid >> 1, ak = (tid & 1) << 4;
    const float* pA = x + (size_t)(bm + ar) * 2048 + ak;
    const int wofs = (tid >> 6) << 10;   // wave LDS byte base for gload

    f32x4 acc[16];
#pragma unroll
    for (int i = 0; i < 16; ++i) acc[i] = (f32x4){0.f, 0.f, 0.f, 0.f};

    for (int kt = 0; kt < 2048; kt += 32) {
        float4 af[4];
#pragma unroll
        for (int i = 0; i < 4; ++i) af[i] = *(const float4*)(pA + kt + (i << 2));
        __syncthreads();   // prev iter frag reads done
#pragma unroll
        for (int j = 0; j < 2; ++j) {
            const int c = (j << 8) + tid;
            const size_t go = (size_t)(bn + (c >> 2)) * 2048 + kt + ((c & 3) << 3);
            gload_lds16(Bth + go, (char*)Bh + (j << 12) + wofs);
            gload_lds16(Btl + go, (char*)Bl + (j << 12) + wofs);
        }
        // split A (truncation hi/lo: exact to 2^-16)
        const float* f = (const float*)af;
        unsigned int hp[8], lp[8];
#pragma unroll
        for (int e = 0; e < 8; ++e) {
            const unsigned int u0 = __float_as_uint(f[2 * e]), u1 = __float_as_uint(f[2 * e + 1]);
            const float l0 = f[2 * e]     - __uint_as_float(u0 & 0xFFFF0000u);
            const float l1 = f[2 * e + 1] - __uint_as_float(u1 & 0xFFFF0000u);
            hp[e] = (u0 >> 16) | (u1 & 0xFFFF0000u);
            lp[e] = (__float_as_uint(l0) >> 16) | (__float_as_uint(l1) & 0xFFFF0000u);
        }
        *(uint4*)&Ah[ar * 32 + ak]     = make_uint4(hp[0], hp[1], hp[2], hp[3]);
        *(uint4*)&Ah[ar * 32 + ak + 8] = make_uint4(hp[4], hp[5], hp[6], hp[7]);
        *(uint4*)&Al[ar * 32 + ak]     = make_uint4(lp[0], lp[1], lp[2], lp[3]);
        *(uint4*)&Al[ar * 32 + ak + 8] = make_uint4(lp[4], lp[5], lp[6], lp[7]);
        __syncthreads();   // staging complete (vmcnt+lgkmcnt drained by barrier)

        bf16x8 a_h[4], a_l[4];
#pragma unroll
        for (int mt = 0; mt < 4; ++mt) {
            const int ao = (wm * 64 + mt * 16 + c16) * 32 + quad * 8;
            a_h[mt] = *(const bf16x8*)&Ah[ao];
            a_l[mt] = *(const bf16x8*)&Al[ao];
        }
#pragma unroll
        for (int nt = 0; nt < 4; ++nt) {
            const int bo = (wn * 64 + nt * 16 + c16) * 32 + quad * 8;
            const bf16x8 b_h = *(const bf16x8*)&Bh[bo];
            const bf16x8 b_l = *(const bf16x8*)&Bl[bo];
#pragma unroll
            for (int mt = 0; mt < 4; ++mt) {
                acc[mt * 4 + nt] = __builtin_amdgcn_mfma_f32_16x16x32_bf16(a_h[mt], b_h, acc[mt * 4 + nt], 0, 0, 0);
                acc[mt * 4 + nt] = __builtin_amdgcn_mfma_f32_16x16x32_bf16(a_l[mt], b_h, acc[mt * 4 + nt], 0, 0, 0);
                acc[mt * 4 + nt] = __builtin_amdgcn_mfma_f32_16x16x32_bf16(a_h[mt], b_l, acc[mt * 4 + nt], 0, 0, 0);
            }
        }
    }

    // epilogue: cls 0 = Q (scaled, row-major qb), 1 = K -> Kr[b,h,t,d], 2 = V -> Vr
    const int cls = bn >> 11;
    const float scl = (cls == 0) ? 0.08838834764831845f : 1.0f;
    const int h = (bn & 2047) >> 7;
    float bv[4];
#pragma unroll
    for (int nt = 0; nt < 4; ++nt) bv[nt] = bias[bn + wn * 64 + nt * 16 + c16];
#pragma unroll
    for (int mt = 0; mt < 4; ++mt) {
#pragma unroll
        for (int r = 0; r < 4; ++r) {
            const int rg = bm + wm * 64 + mt * 16 + quad * 4 + r;
            unsigned short* dst;
            if (cls == 0) {
                dst = qb + (size_t)rg * 2048 + bn;
            } else {
                const int bb = rg >> 11, t = rg & 2047;
                dst = (cls == 1 ? Kr : Vr) + (size_t)(bb * H_NUM + h) * (2048 * 128) + (size_t)t * 128;
            }
#pragma unroll
            for (int nt = 0; nt < 4; ++nt)
                dst[wn * 64 + nt * 16 + c16] = f2bf((acc[mt * 4 + nt][r] + bv[nt]) * scl);
        }
    }
}

// ===== GEMM2: out = (attn_h+attn_l) @ WpT^T + b, hi/lo MFMA, fp32 out =====
__global__ __launch_bounds__(256, 3)
void gemm_proj_mfma(const unsigned short* __restrict__ Ahg, const unsigned short* __restrict__ Alg,
                    const unsigned short* __restrict__ Bth, const unsigned short* __restrict__ Btl,
                    const float* __restrict__ bias, float* __restrict__ out)
{
    __shared__ unsigned short Ah[128 * 32], Al[128 * 32], Bh[128 * 32], Bl[128 * 32];
    const int tid = threadIdx.x;
    const int w = tid >> 6, lane = tid & 63, c16 = lane & 15, quad = lane >> 4;
    const int wm = w & 1, wn = w >> 1;
    const int bm = blockIdx.y << 7, bn = blockIdx.x << 7;
    const int wofs = (tid >> 6) << 10;

    f32x4 acc[16];
#pragma unroll
    for (int i = 0; i < 16; ++i) acc[i] = (f32x4){0.f, 0.f, 0.f, 0.f};

    for (int kt = 0; kt < 2048; kt += 32) {
        __syncthreads();
#pragma unroll
        for (int j = 0; j < 2; ++j) {
            const int c = (j << 8) + tid;
            const size_t ga = (size_t)(bm + (c >> 2)) * 2048 + kt + ((c & 3) << 3);
            const size_t gb = (size_t)(bn + (c >> 2)) * 2048 + kt + ((c & 3) << 3);
            gload_lds16(Ahg + ga, (char*)Ah + (j << 12) + wofs);
            gload_lds16(Alg + ga, (char*)Al + (j << 12) + wofs);
            gload_lds16(Bth + gb, (char*)Bh + (j << 12) + wofs);
            gload_lds16(Btl + gb, (char*)Bl + (j << 12) + wofs);
        }
        __syncthreads();

        bf16x8 a_h[4], a_l[4];
#pragma unroll
        for (int mt = 0; mt < 4; ++mt) {
            const int ao = (wm * 64 + mt * 16 + c16) * 32 + quad * 8;
            a_h[mt] = *(const bf16x8*)&Ah[ao];
            a_l[mt] = *(const bf16x8*)&Al[ao];
        }
#pragma unroll
        for (int nt = 0; nt < 4; ++nt) {
            const int bo = (wn * 64 + nt * 16 + c16) * 32 + quad * 8;
            const bf16x8 b_h = *(const bf16x8*)&Bh[bo];
            const bf16x8 b_l = *(const bf16x8*)&Bl[bo];
#pragma unroll
            for (int mt = 0; mt < 4; ++mt) {
                acc[mt * 4 + nt] = __builtin_amdgcn_mfma_f32_16x16x32_bf16(a_h[mt], b_h, acc[mt * 4 + nt], 0, 0, 0);
                acc[mt * 4 + nt] = __builtin_amdgcn_mfma_f32_16x16x32_bf16(a_l[mt], b_h, acc[mt * 4 + nt], 0, 0, 0);
                acc[mt * 4 + nt] = __builtin_amdgcn_mfma_f32_16x16x32_bf16(a_h[mt], b_l, acc[mt * 4 + nt], 0, 0, 0);
            }
        }
    }

    float bv[4];
#pragma unroll
    for (int nt = 0; nt < 4; ++nt) bv[nt] = bias[bn + wn * 64 + nt * 16 + c16];
#pragma unroll
    for (int mt = 0; mt < 4; ++mt) {
#pragma unroll
        for (int r = 0; r < 4; ++r) {
            const int rg = bm + wm * 64 + mt * 16 + quad * 4 + r;
            float* dst = out + (size_t)rg * 2048 + bn + wn * 64 + c16;
#pragma unroll
            for (int nt = 0; nt < 4; ++nt)
                dst[nt * 16] = acc[mt * 4 + nt][r] + bv[nt];
        }
    }
}

// ===================== MFMA flash attention (bf16, hi/lo out) ================
__global__ __launch_bounds__(256, 3)
void attn_mfma_kernel(const unsigned short* __restrict__ qb,
                      const unsigned short* __restrict__ Kr,
                      const unsigned short* __restrict__ memb,
                      const unsigned short* __restrict__ Vrt,
                      const unsigned short* __restrict__ memt,
                      unsigned short* __restrict__ attn_h,
                      unsigned short* __restrict__ attn_l)
{
    __shared__ unsigned short Qs[64 * 136];
    __shared__ unsigned short Ks[64 * 136];
    __shared__ unsigned short Vts[128 * 72];
    unsigned short* Ps = Ks;

    const int tid = threadIdx.x;
    const int w = tid >> 6, lane = tid & 63;
    const int c16 = lane & 15, quad = lane >> 4;
    const int qt = (int)gridDim.x - 1 - (int)blockIdx.x;
    const int h = blockIdx.y, b = blockIdx.z;
    const int t0 = qt << 6;
    const int bT = b * T_SEQ;
    const int bh = b * H_NUM + h;

    const unsigned short* Krb = Kr + (size_t)bh * (2048 * 128);
    const unsigned short* Vrb = Vrt + (size_t)bh * (2048 * 128);

    {   // stage Q tile (pre-scaled bf16)
        const int r = tid >> 2, ch = (tid & 3) << 5;
        const unsigned short* src = qb + (size_t)(bT + t0 + r) * 2048 + h * D_HEAD + ch;
#pragma unroll
        for (int i = 0; i < 4; ++i)
            *(float4*)&Qs[r * 136 + ch + (i << 3)] = *(const float4*)(src + (i << 3));
    }

    f32x4 acc_o[8];
#pragma unroll
    for (int i = 0; i < 8; ++i) acc_o[i] = (f32x4){0.f, 0.f, 0.f, 0.f};
    float m_r[4] = {-1e30f, -1e30f, -1e30f, -1e30f};
    float l_r[4] = {0.f, 0.f, 0.f, 0.f};

    const int nk = qt + 1;
    const int ntile = nk + (MEM_N >> 6);

    const int sK = tid >> 2, cK = (tid & 3) << 5;
    const int dV = tid >> 1, cV = (tid & 1) << 5;

    float4 kf[4], vf[4];
    {   // prefetch tile 0 (always a real-token tile)
        const unsigned short* kp = Krb + (size_t)sK * 128 + cK;
        const unsigned short* vp = Vrb + (size_t)dV * 2048 + cV;
#pragma unroll
        for (int i = 0; i < 4; ++i) {
            kf[i] = *(const float4*)(kp + (i << 3));
            vf[i] = *(const float4*)(vp + (i << 3));
        }
    }

    for (int it = 0; it < ntile; ++it) {
        __syncthreads();
#pragma unroll
        for (int i = 0; i < 4; ++i) {
            *(float4*)&Ks[sK * 136 + cK + (i << 3)] = kf[i];
            *(float4*)&Vts[dV * 72 + cV + (i << 3)] = vf[i];
        }
        if (it + 1 < ntile) {
            const int nx = it + 1;
            const bool nm = nx >= nk;
            const int sl = nm ? ((nx - nk) << 6) : (nx << 6);
            const unsigned short* kp = nm ? memb + (size_t)(sl + sK) * 2048 + h * D_HEAD + cK
                                          : Krb + (size_t)(sl + sK) * 128 + cK;
            const unsigned short* vp = nm ? memt + (size_t)(h * D_HEAD + dV) * 1024 + sl + cV
                                          : Vrb + (size_t)dV * 2048 + sl + cV;
#pragma unroll
            for (int i = 0; i < 4; ++i) {
                kf[i] = *(const float4*)(kp + (i << 3));
                vf[i] = *(const float4*)(vp + (i << 3));
            }
        }
        __syncthreads();

        f32x4 acc_s[4];
#pragma unroll
        for (int i = 0; i < 4; ++i) acc_s[i] = (f32x4){0.f, 0.f, 0.f, 0.f};
#pragma unroll
        for (int kk = 0; kk < 4; ++kk) {
            const bf16x8 a = *(const bf16x8*)&Qs[(w * 16 + c16) * 136 + (kk << 5) + (quad << 3)];
#pragma unroll
            for (int nt = 0; nt < 4; ++nt) {
                const bf16x8 bb = *(const bf16x8*)&Ks[(nt * 16 + c16) * 136 + (kk << 5) + (quad << 3)];
                acc_s[nt] = __builtin_amdgcn_mfma_f32_16x16x32_bf16(a, bb, acc_s[nt], 0, 0, 0);
            }
        }

        float sv[4][4];
#pragma unroll
        for (int nt = 0; nt < 4; ++nt)
#pragma unroll
            for (int r = 0; r < 4; ++r) sv[nt][r] = acc_s[nt][r];

        if (it == nk - 1) {
#pragma unroll
            for (int nt = 0; nt < 4; ++nt) {
                const int scol = t0 + nt * 16 + c16;
#pragma unroll
                for (int r = 0; r < 4; ++r) {
                    const int trow = t0 + w * 16 + quad * 4 + r;
                    if (scol > trow) sv[nt][r] = -1e30f;
                }
            }
        }

        float mx[4], mn[4], al[4], rs[4], p[4][4];
#pragma unroll
        for (int r = 0; r < 4; ++r)
            mx[r] = fmaxf(fmaxf(sv[0][r], sv[1][r]), fmaxf(sv[2][r], sv[3][r]));
#pragma unroll
        for (int off = 1; off < 16; off <<= 1)
#pragma unroll
            for (int r = 0; r < 4; ++r) mx[r] = fmaxf(mx[r], __shfl_xor(mx[r], off));
#pragma unroll
        for (int r = 0; r < 4; ++r) {
            mn[r] = fmaxf(m_r[r], mx[r]);
            al[r] = __expf(m_r[r] - mn[r]);
            m_r[r] = mn[r];
        }
#pragma unroll
        for (int nt = 0; nt < 4; ++nt)
#pragma unroll
            for (int r = 0; r < 4; ++r) p[nt][r] = __expf(sv[nt][r] - mn[r]);
#pragma unroll
        for (int r = 0; r < 4; ++r) rs[r] = (p[0][r] + p[1][r]) + (p[2][r] + p[3][r]);
#pragma unroll
        for (int off = 1; off < 16; off <<= 1)
#pragma unroll
            for (int r = 0; r < 4; ++r) rs[r] += __shfl_xor(rs[r], off);
#pragma unroll
        for (int r = 0; r < 4; ++r) l_r[r] = l_r[r] * al[r] + rs[r];
#pragma unroll
        for (int nt = 0; nt < 8; ++nt)
#pragma unroll
            for (int r = 0; r < 4; ++r) acc_o[nt][r] *= al[r];

        __syncthreads();
#pragma unroll
        for (int nt = 0; nt < 4; ++nt)
#pragma unroll
            for (int r = 0; r < 4; ++r)
                Ps[(w * 16 + quad * 4 + r) * 72 + nt * 16 + c16] = f2bf(p[nt][r]);
        __syncthreads();

#pragma unroll
        for (int ks = 0; ks < 2; ++ks) {
            const bf16x8 a = *(const bf16x8*)&Ps[(w * 16 + c16) * 72 + (ks << 5) + (quad << 3)];
#pragma unroll
            for (int nt = 0; nt < 8; ++nt) {
                const bf16x8 bb = *(const bf16x8*)&Vts[(nt * 16 + c16) * 72 + (ks << 5) + (quad << 3)];
                acc_o[nt] = __builtin_amdgcn_mfma_f32_16x16x32_bf16(a, bb, acc_o[nt], 0, 0, 0);
            }
        }
    }

    float inv[4];
#pragma unroll
    for (int r = 0; r < 4; ++r) inv[r] = 1.0f / l_r[r];
#pragma unroll
    for (int r = 0; r < 4; ++r) {
        const size_t ro = (size_t)(bT + t0 + w * 16 + quad * 4 + r) * 2048 + h * D_HEAD + c16;
#pragma unroll
        for (int nt = 0; nt < 8; ++nt) {
            const float o = acc_o[nt][r] * inv[r];
            const unsigned int u = __float_as_uint(o);
            const float lo = o - __uint_as_float(u & 0xFFFF0000u);
            attn_h[ro + nt * 16] = (unsigned short)(u >> 16);
            attn_l[ro + nt * 16] = (unsigned short)(__float_as_uint(lo) >> 16);
        }
    }
}

extern "C" void kernel_launch(void* const* d_in, const int* in_sizes, int n_in,
                              void* d_out, int out_size, void* d_ws, size_t ws_size,
                              hipStream_t stream)
{
    const float* x     = (const float*)d_in[0];
    const float* Wqkv  = (const float*)d_in[1];
    const float* bqkv  = (const float*)d_in[2];
    const float* mem   = (const float*)d_in[3];
    const float* Wproj = (const float*)d_in[4];
    const float* bproj = (const float*)d_in[5];
    float* out = (float*)d_out;

    // workspace layout (125.8 MB total)
    unsigned short* ws16 = (unsigned short*)d_ws;
    unsigned short* WqTh = ws16;                         // 12,582,912
    unsigned short* WqTl = WqTh + 12582912;              // 12,582,912
    unsigned short* qb   = WqTl + 12582912;              //  8,388,608
    unsigned short* Kr   = qb   + 8388608;               //  8,388,608
    unsigned short* Vr   = Kr   + 8388608;               //  8,388,608
    unsigned short* Vrt  = Vr   + 8388608;               //  8,388,608
    unsigned short* memb = Vrt  + 8388608;               //  2,097,152
    unsigned short* memt = memb + 2097152;               //  2,097,152
    // overlays: WqT region dead after gemm1
    unsigned short* attn_h = WqTh;                       //  8,388,608
    unsigned short* attn_l = WqTl;
    unsigned short* WpTh = WqTh + 8388608;               //  4,194,304 (tail)
    unsigned short* WpTl = WqTl + 8388608;

    split_w_t<<<dim3(96, 32), 256, 0, stream>>>(Wqkv, WqTh, WqTl, QKV_N);
    split_mem_kernel<<<dim3(32, 16), 256, 0, stream>>>(mem, memb, memt);

    gemm_qkv_mfma<<<dim3(48, 32), 256, 0, stream>>>(x, WqTh, WqTl, bqkv, qb, Kr, Vr);

    split_w_t<<<dim3(32, 32), 256, 0, stream>>>(Wproj, WpTh, WpTl, C_DIM);
    transpose_v_kernel<<<dim3(32, 16, 2), 256, 0, stream>>>(Vr, Vrt);

    attn_mfma_kernel<<<dim3(32, 16, 2), 256, 0, stream>>>(qb, Kr, memb, Vrt, memt, attn_h, attn_l);

    gemm_proj_mfma<<<dim3(16, 32), 256, 0, stream>>>(attn_h, attn_l, WpTh, WpTl, bproj, out);
}

// Round 4
// 831.250 us; speedup vs baseline: 4.1726x; 1.3114x over previous
//
#include <hip/hip_runtime.h>
#include <math.h>

#define T_SEQ  2048
#define C_DIM  2048
#define H_NUM  16
#define D_HEAD 128
#define MEM_N  1024
#define S_ALL  3072
#define QKV_N  6144

typedef __attribute__((ext_vector_type(4))) float f32x4;
typedef __attribute__((ext_vector_type(8))) short bf16x8;
typedef __attribute__((ext_vector_type(8))) unsigned short us8;

__device__ __forceinline__ unsigned short f2bf(float f) {
    unsigned int u = __float_as_uint(f);
    u = (u + 0x7fffu + ((u >> 16) & 1u)) >> 16;   // RNE
    return (unsigned short)u;
}

// async global->LDS, 16B per lane; lds ptr must be wave-uniform (HW adds lane*16)
__device__ __forceinline__ void gload_lds16(const void* g, void* l) {
    __builtin_amdgcn_global_load_lds((const __attribute__((address_space(1))) void*)g,
                                     (__attribute__((address_space(3))) void*)l, 16, 0, 0);
}

// ===== split+transpose W: [K=2048, N] fp32 -> Th/Tl [N][2048] bf16 (hi/lo) =====
__global__ __launch_bounds__(256, 2)
void split_w_t(const float* __restrict__ W, unsigned short* __restrict__ Th,
               unsigned short* __restrict__ Tl, int N)
{
    __shared__ float tile[64][68];
    const int tid = threadIdx.x;
    const int n0 = blockIdx.x << 6, k0 = blockIdx.y << 6;
    const int r = tid >> 2, c4 = (tid & 3) << 4;
    const float* src = W + (size_t)(k0 + r) * N + n0 + c4;
#pragma unroll
    for (int i = 0; i < 4; ++i)
        *(float4*)&tile[r][c4 + (i << 2)] = *(const float4*)(src + (i << 2));
    __syncthreads();
    unsigned int hi[8], lo[8];
#pragma unroll
    for (int e = 0; e < 8; ++e) {
        const float f0 = tile[c4 + 2 * e][r], f1 = tile[c4 + 2 * e + 1][r];
        const unsigned int u0 = __float_as_uint(f0), u1 = __float_as_uint(f1);
        const float l0 = f0 - __uint_as_float(u0 & 0xFFFF0000u);
        const float l1 = f1 - __uint_as_float(u1 & 0xFFFF0000u);
        hi[e] = (u0 >> 16) | (u1 & 0xFFFF0000u);
        lo[e] = (__float_as_uint(l0) >> 16) | (__float_as_uint(l1) & 0xFFFF0000u);
    }
    unsigned short* dh = Th + (size_t)(n0 + r) * 2048 + k0 + c4;
    unsigned short* dl = Tl + (size_t)(n0 + r) * 2048 + k0 + c4;
    *(uint4*)dh       = make_uint4(hi[0], hi[1], hi[2], hi[3]);
    *(uint4*)(dh + 8) = make_uint4(hi[4], hi[5], hi[6], hi[7]);
    *(uint4*)dl       = make_uint4(lo[0], lo[1], lo[2], lo[3]);
    *(uint4*)(dl + 8) = make_uint4(lo[4], lo[5], lo[6], lo[7]);
}

// ===== memory bank: fp32 [1024,2048] -> memb bf16 [1024,2048] + memt bf16 [2048,1024]
__global__ __launch_bounds__(256, 2)
void split_mem_kernel(const float* __restrict__ mem, unsigned short* __restrict__ memb,
                      unsigned short* __restrict__ memt)
{
    __shared__ float tile[64][68];
    const int tid = threadIdx.x;
    const int c0 = blockIdx.x << 6, s0 = blockIdx.y << 6;
    const int r = tid >> 2, c4 = (tid & 3) << 4;
    const float* src = mem + (size_t)(s0 + r) * 2048 + c0 + c4;
    unsigned short* db = memb + (size_t)(s0 + r) * 2048 + c0 + c4;
#pragma unroll
    for (int i = 0; i < 4; ++i) {
        const float4 v = *(const float4*)(src + (i << 2));
        *(float4*)&tile[r][c4 + (i << 2)] = v;
        ushort4 o;
        o.x = f2bf(v.x); o.y = f2bf(v.y); o.z = f2bf(v.z); o.w = f2bf(v.w);
        *(ushort4*)(db + (i << 2)) = o;
    }
    __syncthreads();
    unsigned short* dt = memt + (size_t)(c0 + r) * 1024 + s0 + c4;
#pragma unroll
    for (int i = 0; i < 4; ++i) {
        ushort4 o;
        o.x = f2bf(tile[c4 + (i << 2) + 0][r]);
        o.y = f2bf(tile[c4 + (i << 2) + 1][r]);
        o.z = f2bf(tile[c4 + (i << 2) + 2][r]);
        o.w = f2bf(tile[c4 + (i << 2) + 3][r]);
        *(ushort4*)(dt + (i << 2)) = o;
    }
}

// ===== Vr [b,h,2048,128] bf16 -> Vrt [b,h,128,2048] bf16 =====
__global__ __launch_bounds__(256, 2)
void transpose_v_kernel(const unsigned short* __restrict__ Vr, unsigned short* __restrict__ Vrt)
{
    __shared__ unsigned short Vtmp[64 * 136];
    const int tid = threadIdx.x;
    const int s0 = (int)blockIdx.x << 6;
    const int h = blockIdx.y, b = blockIdx.z;
    const size_t bho = (size_t)(b * H_NUM + h) * (2048 * 128);
    const int sr = tid >> 2, ch = (tid & 3) << 5;
    const unsigned short* vp = Vr + bho + (size_t)(s0 + sr) * 128 + ch;
#pragma unroll
    for (int i = 0; i < 4; ++i)
        *(float4*)&Vtmp[sr * 136 + ch + (i << 3)] = *(const float4*)(vp + (i << 3));
    __syncthreads();
    const int d = tid >> 1, half = tid & 1;
    unsigned short* vd = Vrt + bho + (size_t)d * 2048 + s0 + (half << 5);
#pragma unroll
    for (int c = 0; c < 4; ++c) {
        us8 o;
#pragma unroll
        for (int j = 0; j < 8; ++j)
            o[j] = Vtmp[((half << 5) + (c << 3) + j) * 136 + d];
        *(us8*)(vd + (c << 3)) = o;
    }
}

// ===== GEMM1: qkv = x @ WqT^T + b, hi/lo MFMA; scatter epilogue to qb/Kr/Vr =====
__global__ __launch_bounds__(256, 3)
void gemm_qkv_mfma(const float* __restrict__ x,
                   const unsigned short* __restrict__ Bth, const unsigned short* __restrict__ Btl,
                   const float* __restrict__ bias,
                   unsigned short* __restrict__ qb, unsigned short* __restrict__ Kr,
                   unsigned short* __restrict__ Vr)
{
    __shared__ unsigned short Ah[128 * 32], Al[128 * 32], Bh[128 * 32], Bl[128 * 32];
    const int tid = threadIdx.x;
    const int w = tid >> 6, lane = tid & 63, c16 = lane & 15, quad = lane >> 4;
    const int wm = w & 1, wn = w >> 1;
    const int bm = blockIdx.y << 7, bn = blockIdx.x << 7;

    const int ar = tid >> 1, ak = (tid & 1) << 4;
    const float* pA = x + (size_t)(bm + ar) * 2048 + ak;
    const int wofs = (tid >> 6) << 10;

    f32x4 acc[16];
#pragma unroll
    for (int i = 0; i < 16; ++i) acc[i] = (f32x4){0.f, 0.f, 0.f, 0.f};

    for (int kt = 0; kt < 2048; kt += 32) {
        float4 af[4];
#pragma unroll
        for (int i = 0; i < 4; ++i) af[i] = *(const float4*)(pA + kt + (i << 2));
        __syncthreads();
#pragma unroll
        for (int j = 0; j < 2; ++j) {
            const int c = (j << 8) + tid;
            const size_t go = (size_t)(bn + (c >> 2)) * 2048 + kt + ((c & 3) << 3);
            gload_lds16(Bth + go, (char*)Bh + (j << 12) + wofs);
            gload_lds16(Btl + go, (char*)Bl + (j << 12) + wofs);
        }
        const float* f = (const float*)af;
        unsigned int hp[8], lp[8];
#pragma unroll
        for (int e = 0; e < 8; ++e) {
            const unsigned int u0 = __float_as_uint(f[2 * e]), u1 = __float_as_uint(f[2 * e + 1]);
            const float l0 = f[2 * e]     - __uint_as_float(u0 & 0xFFFF0000u);
            const float l1 = f[2 * e + 1] - __uint_as_float(u1 & 0xFFFF0000u);
            hp[e] = (u0 >> 16) | (u1 & 0xFFFF0000u);
            lp[e] = (__float_as_uint(l0) >> 16) | (__float_as_uint(l1) & 0xFFFF0000u);
        }
        *(uint4*)&Ah[ar * 32 + ak]     = make_uint4(hp[0], hp[1], hp[2], hp[3]);
        *(uint4*)&Ah[ar * 32 + ak + 8] = make_uint4(hp[4], hp[5], hp[6], hp[7]);
        *(uint4*)&Al[ar * 32 + ak]     = make_uint4(lp[0], lp[1], lp[2], lp[3]);
        *(uint4*)&Al[ar * 32 + ak + 8] = make_uint4(lp[4], lp[5], lp[6], lp[7]);
        __syncthreads();

        bf16x8 a_h[4], a_l[4];
#pragma unroll
        for (int mt = 0; mt < 4; ++mt) {
            const int ao = (wm * 64 + mt * 16 + c16) * 32 + quad * 8;
            a_h[mt] = *(const bf16x8*)&Ah[ao];
            a_l[mt] = *(const bf16x8*)&Al[ao];
        }
#pragma unroll
        for (int nt = 0; nt < 4; ++nt) {
            const int bo = (wn * 64 + nt * 16 + c16) * 32 + quad * 8;
            const bf16x8 b_h = *(const bf16x8*)&Bh[bo];
            const bf16x8 b_l = *(const bf16x8*)&Bl[bo];
#pragma unroll
            for (int mt = 0; mt < 4; ++mt) {
                acc[mt * 4 + nt] = __builtin_amdgcn_mfma_f32_16x16x32_bf16(a_h[mt], b_h, acc[mt * 4 + nt], 0, 0, 0);
                acc[mt * 4 + nt] = __builtin_amdgcn_mfma_f32_16x16x32_bf16(a_l[mt], b_h, acc[mt * 4 + nt], 0, 0, 0);
                acc[mt * 4 + nt] = __builtin_amdgcn_mfma_f32_16x16x32_bf16(a_h[mt], b_l, acc[mt * 4 + nt], 0, 0, 0);
            }
        }
    }

    const int cls = bn >> 11;
    const float scl = (cls == 0) ? 0.08838834764831845f : 1.0f;
    const int h = (bn & 2047) >> 7;
    float bv[4];
#pragma unroll
    for (int nt = 0; nt < 4; ++nt) bv[nt] = bias[bn + wn * 64 + nt * 16 + c16];
#pragma unroll
    for (int mt = 0; mt < 4; ++mt) {
#pragma unroll
        for (int r = 0; r < 4; ++r) {
            const int rg = bm + wm * 64 + mt * 16 + quad * 4 + r;
            unsigned short* dst;
            if (cls == 0) {
                dst = qb + (size_t)rg * 2048 + bn;
            } else {
                const int bb = rg >> 11, t = rg & 2047;
                dst = (cls == 1 ? Kr : Vr) + (size_t)(bb * H_NUM + h) * (2048 * 128) + (size_t)t * 128;
            }
#pragma unroll
            for (int nt = 0; nt < 4; ++nt)
                dst[wn * 64 + nt * 16 + c16] = f2bf((acc[mt * 4 + nt][r] + bv[nt]) * scl);
        }
    }
}

// ===== GEMM2: out = (attn_h+attn_l) @ WpT^T + b, hi/lo MFMA, fp32 out =====
__global__ __launch_bounds__(256, 3)
void gemm_proj_mfma(const unsigned short* __restrict__ Ahg, const unsigned short* __restrict__ Alg,
                    const unsigned short* __restrict__ Bth, const unsigned short* __restrict__ Btl,
                    const float* __restrict__ bias, float* __restrict__ out)
{
    __shared__ unsigned short Ah[128 * 32], Al[128 * 32], Bh[128 * 32], Bl[128 * 32];
    const int tid = threadIdx.x;
    const int w = tid >> 6, lane = tid & 63, c16 = lane & 15, quad = lane >> 4;
    const int wm = w & 1, wn = w >> 1;
    const int bm = blockIdx.y << 7, bn = blockIdx.x << 7;
    const int wofs = (tid >> 6) << 10;

    f32x4 acc[16];
#pragma unroll
    for (int i = 0; i < 16; ++i) acc[i] = (f32x4){0.f, 0.f, 0.f, 0.f};

    for (int kt = 0; kt < 2048; kt += 32) {
        __syncthreads();
#pragma unroll
        for (int j = 0; j < 2; ++j) {
            const int c = (j << 8) + tid;
            const size_t ga = (size_t)(bm + (c >> 2)) * 2048 + kt + ((c & 3) << 3);
            const size_t gb = (size_t)(bn + (c >> 2)) * 2048 + kt + ((c & 3) << 3);
            gload_lds16(Ahg + ga, (char*)Ah + (j << 12) + wofs);
            gload_lds16(Alg + ga, (char*)Al + (j << 12) + wofs);
            gload_lds16(Bth + gb, (char*)Bh + (j << 12) + wofs);
            gload_lds16(Btl + gb, (char*)Bl + (j << 12) + wofs);
        }
        __syncthreads();

        bf16x8 a_h[4], a_l[4];
#pragma unroll
        for (int mt = 0; mt < 4; ++mt) {
            const int ao = (wm * 64 + mt * 16 + c16) * 32 + quad * 8;
            a_h[mt] = *(const bf16x8*)&Ah[ao];
            a_l[mt] = *(const bf16x8*)&Al[ao];
        }
#pragma unroll
        for (int nt = 0; nt < 4; ++nt) {
            const int bo = (wn * 64 + nt * 16 + c16) * 32 + quad * 8;
            const bf16x8 b_h = *(const bf16x8*)&Bh[bo];
            const bf16x8 b_l = *(const bf16x8*)&Bl[bo];
#pragma unroll
            for (int mt = 0; mt < 4; ++mt) {
                acc[mt * 4 + nt] = __builtin_amdgcn_mfma_f32_16x16x32_bf16(a_h[mt], b_h, acc[mt * 4 + nt], 0, 0, 0);
                acc[mt * 4 + nt] = __builtin_amdgcn_mfma_f32_16x16x32_bf16(a_l[mt], b_h, acc[mt * 4 + nt], 0, 0, 0);
                acc[mt * 4 + nt] = __builtin_amdgcn_mfma_f32_16x16x32_bf16(a_h[mt], b_l, acc[mt * 4 + nt], 0, 0, 0);
            }
        }
    }

    float bv[4];
#pragma unroll
    for (int nt = 0; nt < 4; ++nt) bv[nt] = bias[bn + wn * 64 + nt * 16 + c16];
#pragma unroll
    for (int mt = 0; mt < 4; ++mt) {
#pragma unroll
        for (int r = 0; r < 4; ++r) {
            const int rg = bm + wm * 64 + mt * 16 + quad * 4 + r;
            float* dst = out + (size_t)rg * 2048 + bn + wn * 64 + c16;
#pragma unroll
            for (int nt = 0; nt < 4; ++nt)
                dst[nt * 16] = acc[mt * 4 + nt][r] + bv[nt];
        }
    }
}

// ============ MFMA flash attention v2: transposed orientation ============
// Block: 128 q-rows x (h,b). 4 waves; wave w owns q in [32w,32w+32) as 2
// B-frag 16-tiles (Q in registers for the whole kernel). Computes
// S^T = K(A) @ Q^T(B)  and  O^T = Vt(A) @ P^T(B). Softmax rows (q) live in
// lanes: 2-shfl reductions. P^T has s along regs -> vectorized b64 LDS writes;
// P region is wave-private (no barrier). 2 barriers/tile (K/V staging only).
// LDS: Ks[64][136] | Vts[128][72] | Ps[128][72] = 54,272 B.
__global__ __launch_bounds__(256, 2)
void attn_mfma_kernel(const unsigned short* __restrict__ qb,
                      const unsigned short* __restrict__ Kr,
                      const unsigned short* __restrict__ memb,
                      const unsigned short* __restrict__ Vrt,
                      const unsigned short* __restrict__ memt,
                      unsigned short* __restrict__ attn_h,
                      unsigned short* __restrict__ attn_l)
{
    __shared__ unsigned short lds[27136];
    unsigned short* Ks  = lds;            // 64*136  = 8704
    unsigned short* Vts = lds + 8704;     // 128*72  = 9216
    unsigned short* Ps  = lds + 17920;    // 128*72  = 9216
    unsigned short* Os  = lds;            // epilogue overlay: 128*136 = 17408

    const int tid = threadIdx.x;
    const int w = tid >> 6, lane = tid & 63;
    const int c16 = lane & 15, quad = lane >> 4;
    const int qt = (int)gridDim.x - 1 - (int)blockIdx.x;  // heavy tiles first
    const int h = blockIdx.y, b = blockIdx.z;
    const int t0 = qt << 7;               // 128-row q tile
    const int bT = b * T_SEQ;
    const int bh = b * H_NUM + h;

    const unsigned short* Krb = Kr + (size_t)bh * (2048 * 128);
    const unsigned short* Vrb = Vrt + (size_t)bh * (2048 * 128);

    // ---- stage Q through LDS (wave-private rows), load B-frags to regs ----
    bf16x8 qfrag[2][4];
    {
        const int row = tid >> 1, co = (tid & 1) << 6;
        const unsigned short* src = qb + (size_t)(bT + t0 + row) * 2048 + h * D_HEAD + co;
#pragma unroll
        for (int i = 0; i < 8; ++i)
            *(float4*)&Os[row * 136 + co + (i << 3)] = *(const float4*)(src + (i << 3));
        // rows [32w,32w+32) written by this wave; frag reads are same-wave (lgkmcnt)
#pragma unroll
        for (int qi = 0; qi < 2; ++qi) {
            const int q = w * 32 + qi * 16 + c16;
#pragma unroll
            for (int kk = 0; kk < 4; ++kk)
                qfrag[qi][kk] = *(const bf16x8*)&Os[q * 136 + (kk << 5) + (quad << 3)];
        }
    }

    f32x4 acc_o[2][8];
#pragma unroll
    for (int qi = 0; qi < 2; ++qi)
#pragma unroll
        for (int i = 0; i < 8; ++i) acc_o[qi][i] = (f32x4){0.f, 0.f, 0.f, 0.f};
    float m_r[2] = {-1e30f, -1e30f};
    float l_r[2] = {0.f, 0.f};

    const int nk = (t0 >> 6) + 2;          // causal s-tiles (64 wide)
    const int ntile = nk + (MEM_N >> 6);

    const int sK = tid >> 2, cK = (tid & 3) << 5;   // K staging: s-row, d-chunk
    const int dV = tid >> 1, cV = (tid & 1) << 5;   // V staging: d-row, s-chunk

    float4 kf[4], vf[4];
    {   // prefetch tile 0 (always causal)
        const unsigned short* kp = Krb + (size_t)sK * 128 + cK;
        const unsigned short* vp = Vrb + (size_t)dV * 2048 + cV;
#pragma unroll
        for (int i = 0; i < 4; ++i) {
            kf[i] = *(const float4*)(kp + (i << 3));
            vf[i] = *(const float4*)(vp + (i << 3));
        }
    }

    for (int it = 0; it < ntile; ++it) {
        const int s0 = (it < nk) ? (it << 6) : (T_SEQ + ((it - nk) << 6));
        __syncthreads();   // prev QK/PV reads of Ks/Vts done (also Q frag loads at it=0)
#pragma unroll
        for (int i = 0; i < 4; ++i) {
            *(float4*)&Ks[sK * 136 + cK + (i << 3)] = kf[i];
            *(float4*)&Vts[dV * 72 + cV + (i << 3)] = vf[i];
        }
        if (it + 1 < ntile) {
            const int nx = it + 1;
            const bool nm = nx >= nk;
            const int sl = nm ? ((nx - nk) << 6) : (nx << 6);
            const unsigned short* kp = nm ? memb + (size_t)(sl + sK) * 2048 + h * D_HEAD + cK
                                          : Krb + (size_t)(sl + sK) * 128 + cK;
            const unsigned short* vp = nm ? memt + (size_t)(h * D_HEAD + dV) * 1024 + sl + cV
                                          : Vrb + (size_t)dV * 2048 + sl + cV;
#pragma unroll
            for (int i = 0; i < 4; ++i) {
                kf[i] = *(const float4*)(kp + (i << 3));
                vf[i] = *(const float4*)(vp + (i << 3));
            }
        }
        __syncthreads();   // Ks/Vts staged

        // ---- S^T = K @ Q^T : C[s=m][q=n]; acc_s[nt][qi], lane q = c16 ----
        f32x4 acc_s[4][2];
#pragma unroll
        for (int nt = 0; nt < 4; ++nt)
#pragma unroll
            for (int qi = 0; qi < 2; ++qi) acc_s[nt][qi] = (f32x4){0.f, 0.f, 0.f, 0.f};
#pragma unroll
        for (int kk = 0; kk < 4; ++kk) {
            bf16x8 ka[4];
#pragma unroll
            for (int nt = 0; nt < 4; ++nt)
                ka[nt] = *(const bf16x8*)&Ks[(nt * 16 + c16) * 136 + (kk << 5) + (quad << 3)];
#pragma unroll
            for (int nt = 0; nt < 4; ++nt)
#pragma unroll
                for (int qi = 0; qi < 2; ++qi)
                    acc_s[nt][qi] = __builtin_amdgcn_mfma_f32_16x16x32_bf16(ka[nt], qfrag[qi][kk], acc_s[nt][qi], 0, 0, 0);
        }

        // mask (causal boundary only): s = s0+nt*16+quad*4+r, q = t0+32w+16qi+c16
        if (it < nk && (s0 + 63 > t0 + (w << 5))) {
#pragma unroll
            for (int nt = 0; nt < 4; ++nt) {
                const int sbase = s0 + nt * 16 + quad * 4;
#pragma unroll
                for (int qi = 0; qi < 2; ++qi) {
                    const int q = t0 + (w << 5) + qi * 16 + c16;
#pragma unroll
                    for (int r = 0; r < 4; ++r)
                        if (sbase + r > q) acc_s[nt][qi][r] = -1e30f;
                }
            }
        }

        // ---- online softmax: q in lanes; reduce over regs + quads (2 shfl) ----
        float mx[2], al[2], rs[2];
#pragma unroll
        for (int qi = 0; qi < 2; ++qi) {
            float m0 = fmaxf(fmaxf(acc_s[0][qi][0], acc_s[0][qi][1]), fmaxf(acc_s[0][qi][2], acc_s[0][qi][3]));
#pragma unroll
            for (int nt = 1; nt < 4; ++nt)
                m0 = fmaxf(m0, fmaxf(fmaxf(acc_s[nt][qi][0], acc_s[nt][qi][1]), fmaxf(acc_s[nt][qi][2], acc_s[nt][qi][3])));
            m0 = fmaxf(m0, __shfl_xor(m0, 16));
            m0 = fmaxf(m0, __shfl_xor(m0, 32));
            mx[qi] = m0;
        }
#pragma unroll
        for (int qi = 0; qi < 2; ++qi) {
            const float mn = fmaxf(m_r[qi], mx[qi]);
            al[qi] = __expf(m_r[qi] - mn);
            m_r[qi] = mn;
            float s = 0.f;
#pragma unroll
            for (int nt = 0; nt < 4; ++nt)
#pragma unroll
                for (int r = 0; r < 4; ++r) {
                    const float p = __expf(acc_s[nt][qi][r] - mn);
                    acc_s[nt][qi][r] = p;
                    s += p;
                }
            rs[qi] = s;
        }
#pragma unroll
        for (int qi = 0; qi < 2; ++qi) {
            rs[qi] += __shfl_xor(rs[qi], 16);
            rs[qi] += __shfl_xor(rs[qi], 32);
            l_r[qi] = l_r[qi] * al[qi] + rs[qi];
#pragma unroll
            for (int dt = 0; dt < 8; ++dt)
#pragma unroll
                for (int r = 0; r < 4; ++r) acc_o[qi][dt][r] *= al[qi];
        }

        // ---- P^T to LDS (wave-private, vectorized, no barrier) ----
#pragma unroll
        for (int qi = 0; qi < 2; ++qi) {
            const int q = (w << 5) + qi * 16 + c16;
#pragma unroll
            for (int nt = 0; nt < 4; ++nt) {
                ushort4 pk;
                pk.x = f2bf(acc_s[nt][qi][0]); pk.y = f2bf(acc_s[nt][qi][1]);
                pk.z = f2bf(acc_s[nt][qi][2]); pk.w = f2bf(acc_s[nt][qi][3]);
                *(ushort4*)&Ps[q * 72 + nt * 16 + quad * 4] = pk;
            }
        }

        // ---- O^T += Vt @ P^T : A = Vts, B = own P columns ----
#pragma unroll
        for (int ks = 0; ks < 2; ++ks) {
            bf16x8 pb[2];
#pragma unroll
            for (int qi = 0; qi < 2; ++qi)
                pb[qi] = *(const bf16x8*)&Ps[((w << 5) + qi * 16 + c16) * 72 + (ks << 5) + (quad << 3)];
#pragma unroll
            for (int dt = 0; dt < 8; ++dt) {
                const bf16x8 va = *(const bf16x8*)&Vts[(dt * 16 + c16) * 72 + (ks << 5) + (quad << 3)];
                acc_o[0][dt] = __builtin_amdgcn_mfma_f32_16x16x32_bf16(va, pb[0], acc_o[0][dt], 0, 0, 0);
                acc_o[1][dt] = __builtin_amdgcn_mfma_f32_16x16x32_bf16(va, pb[1], acc_o[1][dt], 0, 0, 0);
            }
        }
    }

    // ---- epilogue: O^T -> row-major via LDS bounce (wave-private), hi+lo ----
    __syncthreads();   // all PV reads of Vts done; Os overlays Ks+Vts
    const float inv[2] = {1.0f / l_r[0], 1.0f / l_r[1]};
    const int row = tid >> 1, co = (tid & 1) << 6;
    unsigned short* gh = attn_h + (size_t)(bT + t0 + row) * 2048 + h * D_HEAD + co;
    unsigned short* gl = attn_l + (size_t)(bT + t0 + row) * 2048 + h * D_HEAD + co;

#pragma unroll
    for (int pass = 0; pass < 2; ++pass) {
#pragma unroll
        for (int qi = 0; qi < 2; ++qi) {
            const int q = (w << 5) + qi * 16 + c16;
#pragma unroll
            for (int dt = 0; dt < 8; ++dt) {
                ushort4 ov;
                unsigned short* po = (unsigned short*)&ov;
#pragma unroll
                for (int r = 0; r < 4; ++r) {
                    const float o = acc_o[qi][dt][r] * inv[qi];
                    const unsigned int u = __float_as_uint(o);
                    if (pass == 0) {
                        po[r] = (unsigned short)(u >> 16);     // truncated hi
                    } else {
                        const float lo = o - __uint_as_float(u & 0xFFFF0000u);
                        po[r] = f2bf(lo);
                    }
                }
                *(ushort4*)&Os[q * 136 + dt * 16 + quad * 4] = ov;
            }
        }
        // readback rows [32w,32w+32) = this wave's tids (same-wave, lgkmcnt)
        unsigned short* g = (pass == 0) ? gh : gl;
#pragma unroll
        for (int i = 0; i < 8; ++i)
            *(float4*)(g + (i << 3)) = *(const float4*)&Os[row * 136 + co + (i << 3)];
    }
}

extern "C" void kernel_launch(void* const* d_in, const int* in_sizes, int n_in,
                              void* d_out, int out_size, void* d_ws, size_t ws_size,
                              hipStream_t stream)
{
    const float* x     = (const float*)d_in[0];
    const float* Wqkv  = (const float*)d_in[1];
    const float* bqkv  = (const float*)d_in[2];
    const float* mem   = (const float*)d_in[3];
    const float* Wproj = (const float*)d_in[4];
    const float* bproj = (const float*)d_in[5];
    float* out = (float*)d_out;

    unsigned short* ws16 = (unsigned short*)d_ws;
    unsigned short* WqTh = ws16;                         // 12,582,912
    unsigned short* WqTl = WqTh + 12582912;              // 12,582,912
    unsigned short* qb   = WqTl + 12582912;              //  8,388,608
    unsigned short* Kr   = qb   + 8388608;               //  8,388,608
    unsigned short* Vr   = Kr   + 8388608;               //  8,388,608
    unsigned short* Vrt  = Vr   + 8388608;               //  8,388,608
    unsigned short* memb = Vrt  + 8388608;               //  2,097,152
    unsigned short* memt = memb + 2097152;               //  2,097,152
    unsigned short* attn_h = WqTh;                       // overlay (WqT dead)
    unsigned short* attn_l = WqTl;
    unsigned short* WpTh = WqTh + 8388608;
    unsigned short* WpTl = WqTl + 8388608;

    split_w_t<<<dim3(96, 32), 256, 0, stream>>>(Wqkv, WqTh, WqTl, QKV_N);
    split_mem_kernel<<<dim3(32, 16), 256, 0, stream>>>(mem, memb, memt);

    gemm_qkv_mfma<<<dim3(48, 32), 256, 0, stream>>>(x, WqTh, WqTl, bqkv, qb, Kr, Vr);

    split_w_t<<<dim3(32, 32), 256, 0, stream>>>(Wproj, WpTh, WpTl, C_DIM);
    transpose_v_kernel<<<dim3(32, 16, 2), 256, 0, stream>>>(Vr, Vrt);

    attn_mfma_kernel<<<dim3(16, 16, 2), 256, 0, stream>>>(qb, Kr, memb, Vrt, memt, attn_h, attn_l);

    gemm_proj_mfma<<<dim3(16, 32), 256, 0, stream>>>(attn_h, attn_l, WpTh, WpTl, bproj, out);
}

// Round 6
// 662.849 us; speedup vs baseline: 5.2327x; 1.2541x over previous
//
#include <hip/hip_runtime.h>
#include <math.h>

#define T_SEQ  2048
#define C_DIM  2048
#define H_NUM  16
#define D_HEAD 128
#define MEM_N  1024
#define S_ALL  3072
#define QKV_N  6144

typedef __attribute__((ext_vector_type(4))) float f32x4;
typedef __attribute__((ext_vector_type(8))) short bf16x8;
typedef __attribute__((ext_vector_type(8))) unsigned short us8;

__device__ __forceinline__ unsigned short f2bf(float f) {
    unsigned int u = __float_as_uint(f);
    u = (u + 0x7fffu + ((u >> 16) & 1u)) >> 16;   // RNE
    return (unsigned short)u;
}

// async global->LDS, 16B per lane; lds ptr must be wave-uniform (HW adds lane*16)
__device__ __forceinline__ void gload_lds16(const void* g, void* l) {
    __builtin_amdgcn_global_load_lds((const __attribute__((address_space(1))) void*)g,
                                     (__attribute__((address_space(3))) void*)l, 16, 0, 0);
}

// ===== transpose W: [K=2048, N] fp32 -> Th [N][2048] bf16 (RNE) =====
// 2-term hi/lo GEMM keeps A exact, B rounded -> only hi needed.
__global__ __launch_bounds__(256, 2)
void split_w_t(const float* __restrict__ W, unsigned short* __restrict__ Th, int N)
{
    __shared__ float tile[64][68];
    const int tid = threadIdx.x;
    const int n0 = blockIdx.x << 6, k0 = blockIdx.y << 6;
    const int r = tid >> 2, c4 = (tid & 3) << 4;
    const float* src = W + (size_t)(k0 + r) * N + n0 + c4;
#pragma unroll
    for (int i = 0; i < 4; ++i)
        *(float4*)&tile[r][c4 + (i << 2)] = *(const float4*)(src + (i << 2));
    __syncthreads();
    unsigned int hi[8];
#pragma unroll
    for (int e = 0; e < 8; ++e) {
        const unsigned int h0 = f2bf(tile[c4 + 2 * e][r]);
        const unsigned int h1 = f2bf(tile[c4 + 2 * e + 1][r]);
        hi[e] = h0 | (h1 << 16);
    }
    unsigned short* dh = Th + (size_t)(n0 + r) * 2048 + k0 + c4;
    *(uint4*)dh       = make_uint4(hi[0], hi[1], hi[2], hi[3]);
    *(uint4*)(dh + 8) = make_uint4(hi[4], hi[5], hi[6], hi[7]);
}

// ===== memory bank: fp32 [1024,2048] -> memb bf16 [1024,2048] + memt bf16 [2048,1024]
__global__ __launch_bounds__(256, 2)
void split_mem_kernel(const float* __restrict__ mem, unsigned short* __restrict__ memb,
                      unsigned short* __restrict__ memt)
{
    __shared__ float tile[64][68];
    const int tid = threadIdx.x;
    const int c0 = blockIdx.x << 6, s0 = blockIdx.y << 6;
    const int r = tid >> 2, c4 = (tid & 3) << 4;
    const float* src = mem + (size_t)(s0 + r) * 2048 + c0 + c4;
    unsigned short* db = memb + (size_t)(s0 + r) * 2048 + c0 + c4;
#pragma unroll
    for (int i = 0; i < 4; ++i) {
        const float4 v = *(const float4*)(src + (i << 2));
        *(float4*)&tile[r][c4 + (i << 2)] = v;
        ushort4 o;
        o.x = f2bf(v.x); o.y = f2bf(v.y); o.z = f2bf(v.z); o.w = f2bf(v.w);
        *(ushort4*)(db + (i << 2)) = o;
    }
    __syncthreads();
    unsigned short* dt = memt + (size_t)(c0 + r) * 1024 + s0 + c4;
#pragma unroll
    for (int i = 0; i < 4; ++i) {
        ushort4 o;
        o.x = f2bf(tile[c4 + (i << 2) + 0][r]);
        o.y = f2bf(tile[c4 + (i << 2) + 1][r]);
        o.z = f2bf(tile[c4 + (i << 2) + 2][r]);
        o.w = f2bf(tile[c4 + (i << 2) + 3][r]);
        *(ushort4*)(dt + (i << 2)) = o;
    }
}

// ===== Vr [b,h,2048,128] bf16 -> Vrt [b,h,128,2048] bf16 =====
__global__ __launch_bounds__(256, 2)
void transpose_v_kernel(const unsigned short* __restrict__ Vr, unsigned short* __restrict__ Vrt)
{
    __shared__ unsigned short Vtmp[64 * 136];
    const int tid = threadIdx.x;
    const int s0 = (int)blockIdx.x << 6;
    const int h = blockIdx.y, b = blockIdx.z;
    const size_t bho = (size_t)(b * H_NUM + h) * (2048 * 128);
    const int sr = tid >> 2, ch = (tid & 3) << 5;
    const unsigned short* vp = Vr + bho + (size_t)(s0 + sr) * 128 + ch;
#pragma unroll
    for (int i = 0; i < 4; ++i)
        *(float4*)&Vtmp[sr * 136 + ch + (i << 3)] = *(const float4*)(vp + (i << 3));
    __syncthreads();
    const int d = tid >> 1, half = tid & 1;
    unsigned short* vd = Vrt + bho + (size_t)d * 2048 + s0 + (half << 5);
#pragma unroll
    for (int c = 0; c < 4; ++c) {
        us8 o;
#pragma unroll
        for (int j = 0; j < 8; ++j)
            o[j] = Vtmp[((half << 5) + (c << 3) + j) * 136 + d];
        *(us8*)(vd + (c << 3)) = o;
    }
}

// ===== GEMM1: qkv = x @ WqT^T + b, 2-term hi/lo MFMA; scatter to qb/Kr/Vr =====
__global__ __launch_bounds__(256, 3)
void gemm_qkv_mfma(const float* __restrict__ x,
                   const unsigned short* __restrict__ Bth,
                   const float* __restrict__ bias,
                   unsigned short* __restrict__ qb, unsigned short* __restrict__ Kr,
                   unsigned short* __restrict__ Vr)
{
    __shared__ unsigned short Ah[128 * 32], Al[128 * 32], Bh[128 * 32];
    const int tid = threadIdx.x;
    const int w = tid >> 6, lane = tid & 63, c16 = lane & 15, quad = lane >> 4;
    const int wm = w & 1, wn = w >> 1;
    const int bm = blockIdx.y << 7, bn = blockIdx.x << 7;

    const int ar = tid >> 1, ak = (tid & 1) << 4;
    const float* pA = x + (size_t)(bm + ar) * 2048 + ak;
    const int wofs = (tid >> 6) << 10;

    f32x4 acc[16];
#pragma unroll
    for (int i = 0; i < 16; ++i) acc[i] = (f32x4){0.f, 0.f, 0.f, 0.f};

    for (int kt = 0; kt < 2048; kt += 32) {
        float4 af[4];
#pragma unroll
        for (int i = 0; i < 4; ++i) af[i] = *(const float4*)(pA + kt + (i << 2));
        __syncthreads();
#pragma unroll
        for (int j = 0; j < 2; ++j) {
            const int c = (j << 8) + tid;
            const size_t go = (size_t)(bn + (c >> 2)) * 2048 + kt + ((c & 3) << 3);
            gload_lds16(Bth + go, (char*)Bh + (j << 12) + wofs);
        }
        // split A: hi truncated + lo residual (A represented exactly to ~2^-17)
        const float* f = (const float*)af;
        unsigned int hp[8], lp[8];
#pragma unroll
        for (int e = 0; e < 8; ++e) {
            const unsigned int u0 = __float_as_uint(f[2 * e]), u1 = __float_as_uint(f[2 * e + 1]);
            const float l0 = f[2 * e]     - __uint_as_float(u0 & 0xFFFF0000u);
            const float l1 = f[2 * e + 1] - __uint_as_float(u1 & 0xFFFF0000u);
            hp[e] = (u0 >> 16) | (u1 & 0xFFFF0000u);
            lp[e] = (__float_as_uint(l0) >> 16) | (__float_as_uint(l1) & 0xFFFF0000u);
        }
        *(uint4*)&Ah[ar * 32 + ak]     = make_uint4(hp[0], hp[1], hp[2], hp[3]);
        *(uint4*)&Ah[ar * 32 + ak + 8] = make_uint4(hp[4], hp[5], hp[6], hp[7]);
        *(uint4*)&Al[ar * 32 + ak]     = make_uint4(lp[0], lp[1], lp[2], lp[3]);
        *(uint4*)&Al[ar * 32 + ak + 8] = make_uint4(lp[4], lp[5], lp[6], lp[7]);
        __syncthreads();

        bf16x8 a_h[4], a_l[4];
#pragma unroll
        for (int mt = 0; mt < 4; ++mt) {
            const int ao = (wm * 64 + mt * 16 + c16) * 32 + quad * 8;
            a_h[mt] = *(const bf16x8*)&Ah[ao];
            a_l[mt] = *(const bf16x8*)&Al[ao];
        }
#pragma unroll
        for (int nt = 0; nt < 4; ++nt) {
            const int bo = (wn * 64 + nt * 16 + c16) * 32 + quad * 8;
            const bf16x8 b_h = *(const bf16x8*)&Bh[bo];
#pragma unroll
            for (int mt = 0; mt < 4; ++mt) {
                acc[mt * 4 + nt] = __builtin_amdgcn_mfma_f32_16x16x32_bf16(a_h[mt], b_h, acc[mt * 4 + nt], 0, 0, 0);
                acc[mt * 4 + nt] = __builtin_amdgcn_mfma_f32_16x16x32_bf16(a_l[mt], b_h, acc[mt * 4 + nt], 0, 0, 0);
            }
        }
    }

    const int cls = bn >> 11;
    const float scl = (cls == 0) ? 0.08838834764831845f : 1.0f;
    const int h = (bn & 2047) >> 7;
    float bv[4];
#pragma unroll
    for (int nt = 0; nt < 4; ++nt) bv[nt] = bias[bn + wn * 64 + nt * 16 + c16];
#pragma unroll
    for (int mt = 0; mt < 4; ++mt) {
#pragma unroll
        for (int r = 0; r < 4; ++r) {
            const int rg = bm + wm * 64 + mt * 16 + quad * 4 + r;
            unsigned short* dst;
            if (cls == 0) {
                dst = qb + (size_t)rg * 2048 + bn;
            } else {
                const int bb = rg >> 11, t = rg & 2047;
                dst = (cls == 1 ? Kr : Vr) + (size_t)(bb * H_NUM + h) * (2048 * 128) + (size_t)t * 128;
            }
#pragma unroll
            for (int nt = 0; nt < 4; ++nt)
                dst[wn * 64 + nt * 16 + c16] = f2bf((acc[mt * 4 + nt][r] + bv[nt]) * scl);
        }
    }
}

// ===== GEMM2: out = (attn_h+attn_l) @ WpT^T + b, 2-term hi/lo, fp32 out =====
__global__ __launch_bounds__(256, 3)
void gemm_proj_mfma(const unsigned short* __restrict__ Ahg, const unsigned short* __restrict__ Alg,
                    const unsigned short* __restrict__ Bth,
                    const float* __restrict__ bias, float* __restrict__ out)
{
    __shared__ unsigned short Ah[128 * 32], Al[128 * 32], Bh[128 * 32];
    const int tid = threadIdx.x;
    const int w = tid >> 6, lane = tid & 63, c16 = lane & 15, quad = lane >> 4;
    const int wm = w & 1, wn = w >> 1;
    const int bm = blockIdx.y << 7, bn = blockIdx.x << 7;
    const int wofs = (tid >> 6) << 10;

    f32x4 acc[16];
#pragma unroll
    for (int i = 0; i < 16; ++i) acc[i] = (f32x4){0.f, 0.f, 0.f, 0.f};

    for (int kt = 0; kt < 2048; kt += 32) {
        __syncthreads();
#pragma unroll
        for (int j = 0; j < 2; ++j) {
            const int c = (j << 8) + tid;
            const size_t ga = (size_t)(bm + (c >> 2)) * 2048 + kt + ((c & 3) << 3);
            const size_t gb = (size_t)(bn + (c >> 2)) * 2048 + kt + ((c & 3) << 3);
            gload_lds16(Ahg + ga, (char*)Ah + (j << 12) + wofs);
            gload_lds16(Alg + ga, (char*)Al + (j << 12) + wofs);
            gload_lds16(Bth + gb, (char*)Bh + (j << 12) + wofs);
        }
        __syncthreads();

        bf16x8 a_h[4], a_l[4];
#pragma unroll
        for (int mt = 0; mt < 4; ++mt) {
            const int ao = (wm * 64 + mt * 16 + c16) * 32 + quad * 8;
            a_h[mt] = *(const bf16x8*)&Ah[ao];
            a_l[mt] = *(const bf16x8*)&Al[ao];
        }
#pragma unroll
        for (int nt = 0; nt < 4; ++nt) {
            const int bo = (wn * 64 + nt * 16 + c16) * 32 + quad * 8;
            const bf16x8 b_h = *(const bf16x8*)&Bh[bo];
#pragma unroll
            for (int mt = 0; mt < 4; ++mt) {
                acc[mt * 4 + nt] = __builtin_amdgcn_mfma_f32_16x16x32_bf16(a_h[mt], b_h, acc[mt * 4 + nt], 0, 0, 0);
                acc[mt * 4 + nt] = __builtin_amdgcn_mfma_f32_16x16x32_bf16(a_l[mt], b_h, acc[mt * 4 + nt], 0, 0, 0);
            }
        }
    }

    float bv[4];
#pragma unroll
    for (int nt = 0; nt < 4; ++nt) bv[nt] = bias[bn + wn * 64 + nt * 16 + c16];
#pragma unroll
    for (int mt = 0; mt < 4; ++mt) {
#pragma unroll
        for (int r = 0; r < 4; ++r) {
            const int rg = bm + wm * 64 + mt * 16 + quad * 4 + r;
            float* dst = out + (size_t)rg * 2048 + bn + wn * 64 + c16;
#pragma unroll
            for (int nt = 0; nt < 4; ++nt)
                dst[nt * 16] = acc[mt * 4 + nt][r] + bv[nt];
        }
    }
}

// ============ MFMA flash attention (round-4 proven structure) ============
// Transposed orientation: S^T = K(A)@Q^T(B), O^T = Vt(A)@P^T(B). Q in regs,
// P wave-private. Single K/V buffer, 2 barriers/tile. Adds: pair-balance
// swizzle (qt = b ? bx : 15-bx) + per-wave skip of fully-masked diag tiles.
// LDS: Ks[64*136] + Vts[128*72] + Ps[128*72] = 54,272 B (2 blocks/CU).
__global__ __launch_bounds__(256, 2)
void attn_mfma_kernel(const unsigned short* __restrict__ qb,
                      const unsigned short* __restrict__ Kr,
                      const unsigned short* __restrict__ memb,
                      const unsigned short* __restrict__ Vrt,
                      const unsigned short* __restrict__ memt,
                      unsigned short* __restrict__ attn_h,
                      unsigned short* __restrict__ attn_l)
{
    __shared__ unsigned short lds[27136];
    unsigned short* Ks  = lds;            // 64*136  = 8704 u16
    unsigned short* Vts = lds + 8704;     // 128*72  = 9216 u16
    unsigned short* Ps  = lds + 17920;    // 128*72  = 9216 u16
    unsigned short* Os  = lds;            // overlay (Q stage / epilogue), 128*136

    const int tid = threadIdx.x;
    const int w = tid >> 6, lane = tid & 63;
    const int c16 = lane & 15, quad = lane >> 4;
    const int bx = blockIdx.x;
    const int h = blockIdx.y, b = blockIdx.z;
    // balance swizzle: co-resident pair (block i, i+256) gets qt x and 15-x
    const int qt = b ? bx : (15 - bx);
    const int t0 = qt << 7;               // 128-row q tile
    const int bT = b * T_SEQ;
    const int bh = b * H_NUM + h;

    const unsigned short* Krb = Kr + (size_t)bh * (2048 * 128);
    const unsigned short* Vrb = Vrt + (size_t)bh * (2048 * 128);

    // ---- stage Q through LDS (wave-private rows), load B-frags to regs ----
    bf16x8 qfrag[2][4];
    {
        const int row = tid >> 1, co = (tid & 1) << 6;
        const unsigned short* src = qb + (size_t)(bT + t0 + row) * 2048 + h * D_HEAD + co;
#pragma unroll
        for (int i = 0; i < 8; ++i)
            *(float4*)&Os[row * 136 + co + (i << 3)] = *(const float4*)(src + (i << 3));
#pragma unroll
        for (int qi = 0; qi < 2; ++qi) {
            const int q = w * 32 + qi * 16 + c16;
#pragma unroll
            for (int kk = 0; kk < 4; ++kk)
                qfrag[qi][kk] = *(const bf16x8*)&Os[q * 136 + (kk << 5) + (quad << 3)];
        }
    }

    f32x4 acc_o[2][8];
#pragma unroll
    for (int qi = 0; qi < 2; ++qi)
#pragma unroll
        for (int i = 0; i < 8; ++i) acc_o[qi][i] = (f32x4){0.f, 0.f, 0.f, 0.f};
    float m_r[2] = {-1e30f, -1e30f};
    float l_r[2] = {0.f, 0.f};

    const int nk = (t0 >> 6) + 2;          // causal s-tiles (64 wide)
    const int ntile = nk + (MEM_N >> 6);

    const int sK = tid >> 2, cK = (tid & 3) << 5;   // K staging: s-row, d-chunk
    const int dV = tid >> 1, cV = (tid & 1) << 5;   // V staging: d-row, s-chunk

    float4 kf[4], vf[4];
    {   // prefetch tile 0 (always causal)
        const unsigned short* kp = Krb + (size_t)sK * 128 + cK;
        const unsigned short* vp = Vrb + (size_t)dV * 2048 + cV;
#pragma unroll
        for (int i = 0; i < 4; ++i) {
            kf[i] = *(const float4*)(kp + (i << 3));
            vf[i] = *(const float4*)(vp + (i << 3));
        }
    }

    for (int it = 0; it < ntile; ++it) {
        const int s0 = (it < nk) ? (it << 6) : (T_SEQ + ((it - nk) << 6));
        __syncthreads();   // prev QK/PV reads of Ks/Vts done (also Q frag loads at it=0)
#pragma unroll
        for (int i = 0; i < 4; ++i) {
            *(float4*)&Ks[sK * 136 + cK + (i << 3)] = kf[i];
            *(float4*)&Vts[dV * 72 + cV + (i << 3)] = vf[i];
        }
        if (it + 1 < ntile) {
            const int nx = it + 1;
            const bool nm = nx >= nk;
            const int sl = nm ? ((nx - nk) << 6) : (nx << 6);
            const unsigned short* kp = nm ? memb + (size_t)(sl + sK) * 2048 + h * D_HEAD + cK
                                          : Krb + (size_t)(sl + sK) * 128 + cK;
            const unsigned short* vp = nm ? memt + (size_t)(h * D_HEAD + dV) * 1024 + sl + cV
                                          : Vrb + (size_t)dV * 2048 + sl + cV;
#pragma unroll
            for (int i = 0; i < 4; ++i) {
                kf[i] = *(const float4*)(kp + (i << 3));
                vf[i] = *(const float4*)(vp + (i << 3));
            }
        }
        __syncthreads();   // Ks/Vts staged

        // wave-level skip: tile fully masked for this wave's q rows
        // (exact: all p would be 0 and m/l/O unchanged)
        const bool active = (it >= nk) || (s0 <= t0 + (w << 5) + 31);
        if (active) {
            // ---- S^T = K @ Q^T ----
            f32x4 acc_s[4][2];
#pragma unroll
            for (int nt = 0; nt < 4; ++nt)
#pragma unroll
                for (int qi = 0; qi < 2; ++qi) acc_s[nt][qi] = (f32x4){0.f, 0.f, 0.f, 0.f};
#pragma unroll
            for (int kk = 0; kk < 4; ++kk) {
                bf16x8 ka[4];
#pragma unroll
                for (int nt = 0; nt < 4; ++nt)
                    ka[nt] = *(const bf16x8*)&Ks[(nt * 16 + c16) * 136 + (kk << 5) + (quad << 3)];
#pragma unroll
                for (int nt = 0; nt < 4; ++nt)
#pragma unroll
                    for (int qi = 0; qi < 2; ++qi)
                        acc_s[nt][qi] = __builtin_amdgcn_mfma_f32_16x16x32_bf16(ka[nt], qfrag[qi][kk], acc_s[nt][qi], 0, 0, 0);
            }

            // causal boundary mask: s = s0+nt*16+quad*4+r, q = t0+32w+16qi+c16
            if (it < nk && (s0 + 63 > t0 + (w << 5))) {
#pragma unroll
                for (int nt = 0; nt < 4; ++nt) {
                    const int sbase = s0 + nt * 16 + quad * 4;
#pragma unroll
                    for (int qi = 0; qi < 2; ++qi) {
                        const int q = t0 + (w << 5) + qi * 16 + c16;
#pragma unroll
                        for (int r = 0; r < 4; ++r)
                            if (sbase + r > q) acc_s[nt][qi][r] = -1e30f;
                    }
                }
            }

            // ---- online softmax (q in lanes; 2 shfl per reduction) ----
            float mx[2], al[2], rs[2];
#pragma unroll
            for (int qi = 0; qi < 2; ++qi) {
                float m0 = fmaxf(fmaxf(acc_s[0][qi][0], acc_s[0][qi][1]), fmaxf(acc_s[0][qi][2], acc_s[0][qi][3]));
#pragma unroll
                for (int nt = 1; nt < 4; ++nt)
                    m0 = fmaxf(m0, fmaxf(fmaxf(acc_s[nt][qi][0], acc_s[nt][qi][1]), fmaxf(acc_s[nt][qi][2], acc_s[nt][qi][3])));
                m0 = fmaxf(m0, __shfl_xor(m0, 16));
                m0 = fmaxf(m0, __shfl_xor(m0, 32));
                mx[qi] = m0;
            }
#pragma unroll
            for (int qi = 0; qi < 2; ++qi) {
                const float mn = fmaxf(m_r[qi], mx[qi]);
                al[qi] = __expf(m_r[qi] - mn);
                m_r[qi] = mn;
                float s = 0.f;
#pragma unroll
                for (int nt = 0; nt < 4; ++nt)
#pragma unroll
                    for (int r = 0; r < 4; ++r) {
                        const float p = __expf(acc_s[nt][qi][r] - mn);
                        acc_s[nt][qi][r] = p;
                        s += p;
                    }
                rs[qi] = s;
            }
#pragma unroll
            for (int qi = 0; qi < 2; ++qi) {
                rs[qi] += __shfl_xor(rs[qi], 16);
                rs[qi] += __shfl_xor(rs[qi], 32);
                l_r[qi] = l_r[qi] * al[qi] + rs[qi];
#pragma unroll
                for (int dt = 0; dt < 8; ++dt)
#pragma unroll
                    for (int r = 0; r < 4; ++r) acc_o[qi][dt][r] *= al[qi];
            }

            // ---- P^T to LDS (wave-private, vectorized, no barrier) ----
#pragma unroll
            for (int qi = 0; qi < 2; ++qi) {
                const int q = (w << 5) + qi * 16 + c16;
#pragma unroll
                for (int nt = 0; nt < 4; ++nt) {
                    ushort4 pk;
                    pk.x = f2bf(acc_s[nt][qi][0]); pk.y = f2bf(acc_s[nt][qi][1]);
                    pk.z = f2bf(acc_s[nt][qi][2]); pk.w = f2bf(acc_s[nt][qi][3]);
                    *(ushort4*)&Ps[q * 72 + nt * 16 + quad * 4] = pk;
                }
            }

            // ---- O^T += Vt @ P^T ----
#pragma unroll
            for (int ks = 0; ks < 2; ++ks) {
                bf16x8 pb[2];
#pragma unroll
                for (int qi = 0; qi < 2; ++qi)
                    pb[qi] = *(const bf16x8*)&Ps[((w << 5) + qi * 16 + c16) * 72 + (ks << 5) + (quad << 3)];
#pragma unroll
                for (int dt = 0; dt < 8; ++dt) {
                    const bf16x8 va = *(const bf16x8*)&Vts[(dt * 16 + c16) * 72 + (ks << 5) + (quad << 3)];
                    acc_o[0][dt] = __builtin_amdgcn_mfma_f32_16x16x32_bf16(va, pb[0], acc_o[0][dt], 0, 0, 0);
                    acc_o[1][dt] = __builtin_amdgcn_mfma_f32_16x16x32_bf16(va, pb[1], acc_o[1][dt], 0, 0, 0);
                }
            }
        }
    }

    // ---- epilogue: O^T -> row-major via LDS bounce (wave-private), hi+lo ----
    __syncthreads();   // all PV reads of Vts done; Os overlays Ks+Vts
    const float inv[2] = {1.0f / l_r[0], 1.0f / l_r[1]};
    const int row = tid >> 1, co = (tid & 1) << 6;
    unsigned short* gh = attn_h + (size_t)(bT + t0 + row) * 2048 + h * D_HEAD + co;
    unsigned short* gl = attn_l + (size_t)(bT + t0 + row) * 2048 + h * D_HEAD + co;

#pragma unroll
    for (int pass = 0; pass < 2; ++pass) {
#pragma unroll
        for (int qi = 0; qi < 2; ++qi) {
            const int q = (w << 5) + qi * 16 + c16;
#pragma unroll
            for (int dt = 0; dt < 8; ++dt) {
                ushort4 ov;
                unsigned short* po = (unsigned short*)&ov;
#pragma unroll
                for (int r = 0; r < 4; ++r) {
                    const float o = acc_o[qi][dt][r] * inv[qi];
                    const unsigned int u = __float_as_uint(o);
                    if (pass == 0) {
                        po[r] = (unsigned short)(u >> 16);     // truncated hi
                    } else {
                        const float lo = o - __uint_as_float(u & 0xFFFF0000u);
                        po[r] = f2bf(lo);
                    }
                }
                *(ushort4*)&Os[q * 136 + dt * 16 + quad * 4] = ov;
            }
        }
        unsigned short* g = (pass == 0) ? gh : gl;
#pragma unroll
        for (int i = 0; i < 8; ++i)
            *(float4*)(g + (i << 3)) = *(const float4*)&Os[row * 136 + co + (i << 3)];
    }
}

extern "C" void kernel_launch(void* const* d_in, const int* in_sizes, int n_in,
                              void* d_out, int out_size, void* d_ws, size_t ws_size,
                              hipStream_t stream)
{
    const float* x     = (const float*)d_in[0];
    const float* Wqkv  = (const float*)d_in[1];
    const float* bqkv  = (const float*)d_in[2];
    const float* mem   = (const float*)d_in[3];
    const float* Wproj = (const float*)d_in[4];
    const float* bproj = (const float*)d_in[5];
    float* out = (float*)d_out;

    unsigned short* ws16 = (unsigned short*)d_ws;
    unsigned short* WqTh = ws16;                         // 12,582,912
    unsigned short* rgn2 = WqTh + 12582912;              // 12,582,912 (attn_l + WpT tail)
    unsigned short* qb   = rgn2 + 12582912;              //  8,388,608
    unsigned short* Kr   = qb   + 8388608;               //  8,388,608
    unsigned short* Vr   = Kr   + 8388608;               //  8,388,608
    unsigned short* Vrt  = Vr   + 8388608;               //  8,388,608
    unsigned short* memb = Vrt  + 8388608;               //  2,097,152
    unsigned short* memt = memb + 2097152;               //  2,097,152
    unsigned short* attn_h = WqTh;                       // overlay (WqTh dead after gemm1)
    unsigned short* attn_l = rgn2;
    unsigned short* WpTh = rgn2 + 8388608;               //  4,194,304 tail

    split_w_t<<<dim3(96, 32), 256, 0, stream>>>(Wqkv, WqTh, QKV_N);
    split_mem_kernel<<<dim3(32, 16), 256, 0, stream>>>(mem, memb, memt);

    gemm_qkv_mfma<<<dim3(48, 32), 256, 0, stream>>>(x, WqTh, bqkv, qb, Kr, Vr);

    split_w_t<<<dim3(32, 32), 256, 0, stream>>>(Wproj, WpTh, C_DIM);
    transpose_v_kernel<<<dim3(32, 16, 2), 256, 0, stream>>>(Vr, Vrt);

    attn_mfma_kernel<<<dim3(16, 16, 2), 256, 0, stream>>>(qb, Kr, memb, Vrt, memt, attn_h, attn_l);

    gemm_proj_mfma<<<dim3(16, 32), 256, 0, stream>>>(attn_h, attn_l, WpTh, bproj, out);
}